// Round 1
// baseline (218.505 us; speedup 1.0000x reference)
//
#include <hip/hip_runtime.h>
#include <hip/hip_bf16.h>
#include <math.h>

#define B 4
#define T 128
#define S 512
#define H 512

// fast tanh: tanh(x) = 1 - 2/(e^{2x}+1).  v_exp_f32 + v_rcp_f32.
// Saturates correctly: e=inf -> rcp=0 -> +1 ; e=0 -> rcp=1 -> -1.
__device__ __forceinline__ float fast_tanh(float x) {
    float e = __expf(2.0f * x);
    float r = __builtin_amdgcn_rcpf(e + 1.0f);
    return 1.0f - 2.0f * r;
}

// C[m,n] = sum_k A[m,k] * Wt[n,k]   (both operands K-contiguous)
// optional epilogue: C = tanh(C + bias[n])
__global__ __launch_bounds__(256) void gemm_atn(
    const float* __restrict__ A, const float* __restrict__ Wt,
    const float* __restrict__ bias, float* __restrict__ C,
    int M, int N, int K, int do_tanh) {
    __shared__ float As[16][68];
    __shared__ float Bs[16][68];
    const int tid = threadIdx.x;
    const int lk = tid & 15;    // k within tile
    const int lr = tid >> 4;    // row group
    const int tx = tid & 15;    // n micro-tile
    const int ty = tid >> 4;    // m micro-tile
    const int bm = blockIdx.y * 64;
    const int bn = blockIdx.x * 64;
    float acc[4][4] = {};
    for (int k0 = 0; k0 < K; k0 += 16) {
#pragma unroll
        for (int i = 0; i < 4; ++i) {
            As[lk][lr + 16 * i] = A[(size_t)(bm + lr + 16 * i) * K + k0 + lk];
            Bs[lk][lr + 16 * i] = Wt[(size_t)(bn + lr + 16 * i) * K + k0 + lk];
        }
        __syncthreads();
#pragma unroll
        for (int kk = 0; kk < 16; ++kk) {
            float a[4], w[4];
#pragma unroll
            for (int i = 0; i < 4; ++i) a[i] = As[kk][ty * 4 + i];
#pragma unroll
            for (int j = 0; j < 4; ++j) w[j] = Bs[kk][tx * 4 + j];
#pragma unroll
            for (int i = 0; i < 4; ++i)
#pragma unroll
                for (int j = 0; j < 4; ++j)
                    acc[i][j] = fmaf(a[i], w[j], acc[i][j]);
        }
        __syncthreads();
    }
#pragma unroll
    for (int i = 0; i < 4; ++i) {
        int m = bm + ty * 4 + i;
#pragma unroll
        for (int j = 0; j < 4; ++j) {
            int n = bn + tx * 4 + j;
            float x = acc[i][j];
            if (do_tanh) x = fast_tanh(x + bias[n]);
            C[(size_t)m * N + n] = x;
        }
    }
}

// One block per (b,t): score over s (skip masked s>=L), softmax, context.
// Writes cq[bt] = [context(512) | query(512)].
__global__ __launch_bounds__(256) void attn_ctx(
    const float* __restrict__ qp, const float* __restrict__ kp,
    const float* __restrict__ enc, const float* __restrict__ v,
    const int* __restrict__ src_len, const float* __restrict__ query,
    float* __restrict__ cq) {
    __shared__ float attn[S];
    __shared__ float red[8];
    const int bt = blockIdx.x;
    const int b = bt >> 7;          // T = 128
    const int tid = threadIdx.x;
    const int lane = tid & 63;
    const int wv = tid >> 6;
    const int L = src_len[b];       // 1..512 guaranteed

    // per-lane h-chunk: h in [lane*8, lane*8+8)
    float q[8], vv[8];
    {
        const float4* q4 = reinterpret_cast<const float4*>(qp + (size_t)bt * H) + lane * 2;
        const float4* v4 = reinterpret_cast<const float4*>(v) + lane * 2;
        float4 qa = q4[0], qb = q4[1], va = v4[0], vb = v4[1];
        q[0]=qa.x; q[1]=qa.y; q[2]=qa.z; q[3]=qa.w; q[4]=qb.x; q[5]=qb.y; q[6]=qb.z; q[7]=qb.w;
        vv[0]=va.x; vv[1]=va.y; vv[2]=va.z; vv[3]=va.w; vv[4]=vb.x; vv[5]=vb.y; vv[6]=vb.z; vv[7]=vb.w;
    }

    const float* kpb = kp + (size_t)b * S * H;
    for (int s = wv; s < L; s += 4) {
        const float4* k4 = reinterpret_cast<const float4*>(kpb + (size_t)s * H) + lane * 2;
        float4 ka = k4[0], kb = k4[1];
        float kv[8] = {ka.x, ka.y, ka.z, ka.w, kb.x, kb.y, kb.z, kb.w};
        float acc = 0.f;
#pragma unroll
        for (int i = 0; i < 8; ++i)
            acc = fmaf(vv[i], fast_tanh(q[i] + kv[i]), acc);
#pragma unroll
        for (int off = 32; off > 0; off >>= 1)
            acc += __shfl_down(acc, off);
        if (lane == 0) attn[s] = acc;
    }
    __syncthreads();

    // masked softmax over s (each thread owns s = tid and tid+256)
    float x0 = attn[tid], x1 = attn[tid + 256];
    if (tid >= L) x0 = -INFINITY;
    if (tid + 256 >= L) x1 = -INFINITY;
    float mx = fmaxf(x0, x1);
#pragma unroll
    for (int off = 32; off > 0; off >>= 1)
        mx = fmaxf(mx, __shfl_down(mx, off));
    if (lane == 0) red[wv] = mx;
    __syncthreads();
    mx = fmaxf(fmaxf(red[0], red[1]), fmaxf(red[2], red[3]));
    float e0 = __expf(x0 - mx), e1 = __expf(x1 - mx);
    float sm = e0 + e1;
#pragma unroll
    for (int off = 32; off > 0; off >>= 1)
        sm += __shfl_down(sm, off);
    if (lane == 0) red[4 + wv] = sm;
    __syncthreads();
    float inv = 1.0f / (red[4] + red[5] + red[6] + red[7]);
    attn[tid] = e0 * inv;
    attn[tid + 256] = e1 * inv;
    __syncthreads();

    // context[h] = sum_s attn[s] * enc[b,s,h]; thread owns h=tid, tid+256
    float a0 = 0.f, a1 = 0.f;
    const float* eb = enc + (size_t)b * S * H;
    for (int s = 0; s < L; ++s) {
        float w = attn[s];
        a0 = fmaf(w, eb[(size_t)s * H + tid], a0);
        a1 = fmaf(w, eb[(size_t)s * H + tid + 256], a1);
    }
    float* cqr = cq + (size_t)bt * (2 * H);
    cqr[tid] = a0;
    cqr[tid + 256] = a1;
    cqr[H + tid] = query[(size_t)bt * H + tid];
    cqr[H + tid + 256] = query[(size_t)bt * H + tid + 256];
}

// per-row LayerNorm over H=512; block per row
__global__ __launch_bounds__(256) void ln_out(
    const float* __restrict__ X, const float* __restrict__ gamma,
    const float* __restrict__ beta, float* __restrict__ out) {
    __shared__ float red[8];
    const int r = blockIdx.x;
    const int tid = threadIdx.x;
    const int lane = tid & 63, wv = tid >> 6;
    const float* x = X + (size_t)r * H;
    float x0 = x[tid], x1 = x[tid + 256];
    float s = x0 + x1;
#pragma unroll
    for (int off = 32; off > 0; off >>= 1) s += __shfl_down(s, off);
    if (lane == 0) red[wv] = s;
    __syncthreads();
    float mu = (red[0] + red[1] + red[2] + red[3]) * (1.0f / H);
    float d0 = x0 - mu, d1 = x1 - mu;
    float vsum = d0 * d0 + d1 * d1;
#pragma unroll
    for (int off = 32; off > 0; off >>= 1) vsum += __shfl_down(vsum, off);
    if (lane == 0) red[4 + wv] = vsum;
    __syncthreads();
    float var = (red[4] + red[5] + red[6] + red[7]) * (1.0f / H);
    float inv = rsqrtf(var + 1e-5f);
    out[(size_t)r * H + tid] = d0 * inv * gamma[tid] + beta[tid];
    out[(size_t)r * H + tid + 256] = d1 * inv * gamma[tid + 256] + beta[tid + 256];
}

extern "C" void kernel_launch(void* const* d_in, const int* in_sizes, int n_in,
                              void* d_out, int out_size, void* d_ws, size_t ws_size,
                              hipStream_t stream) {
    const float* query = (const float*)d_in[0];
    const float* enc   = (const float*)d_in[1];
    const int*   slen  = (const int*)d_in[2];
    const float* W_h   = (const float*)d_in[3];
    const float* W_s   = (const float*)d_in[4];
    const float* v     = (const float*)d_in[5];
    const float* W_out = (const float*)d_in[6];
    const float* b_out = (const float*)d_in[7];
    const float* gamma = (const float*)d_in[8];
    const float* beta  = (const float*)d_in[9];
    float* out = (float*)d_out;

    // workspace layout (8 MB total)
    float* qp  = (float*)d_ws;          // 512*512   q_proj
    float* kp  = qp + 512 * 512;        // 2048*512  k_proj
    float* cq  = kp + 2048 * 512;       // 512*1024  [context|query]
    float* pre = cq + 512 * 1024;       // 512*512   pre-LN output

    dim3 blk(256);
    // q_proj = query @ W_s^T   (M=512, N=512, K=512)
    gemm_atn<<<dim3(8, 8), blk, 0, stream>>>(query, W_s, nullptr, qp, 512, 512, 512, 0);
    // k_proj = enc @ W_h^T     (M=2048, N=512, K=512)
    gemm_atn<<<dim3(8, 32), blk, 0, stream>>>(enc, W_h, nullptr, kp, 2048, 512, 512, 0);
    // score -> softmax -> context -> cq
    attn_ctx<<<dim3(512), blk, 0, stream>>>(qp, kp, enc, v, slen, query, cq);
    // pre = tanh(cq @ W_out^T + b_out)  (M=512, N=512, K=1024)
    gemm_atn<<<dim3(8, 8), blk, 0, stream>>>(cq, W_out, b_out, pre, 512, 512, 1024, 1);
    // LayerNorm
    ln_out<<<dim3(512), blk, 0, stream>>>(pre, gamma, beta, out);
}

// Round 2
// 211.637 us; speedup vs baseline: 1.0324x; 1.0324x over previous
//
#include <hip/hip_runtime.h>
#include <hip/hip_bf16.h>
#include <math.h>

#define B 4
#define T 128
#define S 512
#define H 512
// 2*log2(e): fold tanh's 2x and exp2 conversion into the projection epilogue
#define QK_SCALE 2.8853900817779268f

__device__ __forceinline__ float fast_tanh(float x) {
    float e = __expf(2.0f * x);
    float r = __builtin_amdgcn_rcpf(e + 1.0f);
    return 1.0f - 2.0f * r;
}

// C[m,n] = sum_k A'[m,k] * Wt[n,k]; A' = [A | A2] split at ksplit (row strides
// ksplit and K-ksplit). Epilogue: do_tanh ? tanh(C + bias[n]) : C * scale.
__global__ __launch_bounds__(256) void gemm_atn(
    const float* __restrict__ A, const float* __restrict__ A2, int ksplit,
    const float* __restrict__ Wt, const float* __restrict__ bias,
    float* __restrict__ C, int M, int N, int K, int do_tanh, float scale) {
    __shared__ __align__(16) float As[16][68];
    __shared__ __align__(16) float Bs[16][68];
    const int tid = threadIdx.x;
    const int lk = tid & 15;
    const int lr = tid >> 4;
    const int tx = tid & 15;
    const int ty = tid >> 4;
    const int bm = blockIdx.y * 64;
    const int bn = blockIdx.x * 64;
    float acc[4][4] = {};
    for (int k0 = 0; k0 < K; k0 += 16) {
        const float* Ab;
        int kloc, astr;
        if (k0 < ksplit) { Ab = A; kloc = k0; astr = ksplit; }
        else             { Ab = A2; kloc = k0 - ksplit; astr = K - ksplit; }
#pragma unroll
        for (int i = 0; i < 4; ++i) {
            As[lk][lr + 16 * i] = Ab[(size_t)(bm + lr + 16 * i) * astr + kloc + lk];
            Bs[lk][lr + 16 * i] = Wt[(size_t)(bn + lr + 16 * i) * K + k0 + lk];
        }
        __syncthreads();
#pragma unroll
        for (int kk = 0; kk < 16; ++kk) {
            float4 av = *(const float4*)&As[kk][ty * 4];
            float4 wv = *(const float4*)&Bs[kk][tx * 4];
            float a[4] = {av.x, av.y, av.z, av.w};
            float w[4] = {wv.x, wv.y, wv.z, wv.w};
#pragma unroll
            for (int i = 0; i < 4; ++i)
#pragma unroll
                for (int j = 0; j < 4; ++j)
                    acc[i][j] = fmaf(a[i], w[j], acc[i][j]);
        }
        __syncthreads();
    }
#pragma unroll
    for (int i = 0; i < 4; ++i) {
        int m = bm + ty * 4 + i;
#pragma unroll
        for (int j = 0; j < 4; ++j) {
            int n = bn + tx * 4 + j;
            float x = acc[i][j];
            if (do_tanh) x = fast_tanh(x + bias[n]);
            else x *= scale;
            C[(size_t)m * N + n] = x;
        }
    }
}

// score'[b,t,s] = -sum_h 2*v[h] * rcp(exp2(qp2[t,h]+kp2[s,h]) + 1)
// where qp2/kp2 are pre-scaled by 2*log2e. True score = score' + const(sum v),
// which softmax ignores. Block: 32t x 32s tile for one b; skip masked s-tiles.
__global__ __launch_bounds__(256) void score_tile(
    const float* __restrict__ qp, const float* __restrict__ kp,
    const float* __restrict__ v, const int* __restrict__ slen,
    float* __restrict__ score) {
    const int b = blockIdx.z;
    const int L = slen[b];
    const int sbase = blockIdx.x * 32;
    if (sbase >= L) return;
    const int tbase = blockIdx.y * 32;
    __shared__ float qs[32][33];
    __shared__ float ks[32][33];
    __shared__ float vs[32];
    const int tid = threadIdx.x;
    const int tx = tid & 15;       // s microtile (2 per thread)
    const int ty = tid >> 4;       // t microtile (2 per thread)
    float acc[2][2] = {};
    for (int h0 = 0; h0 < H; h0 += 32) {
        const int r = tid >> 3, c = (tid & 7) * 4;
        float4 qv = *(const float4*)&qp[(size_t)(b * T + tbase + r) * H + h0 + c];
        float4 kv = *(const float4*)&kp[(size_t)(b * S + sbase + r) * H + h0 + c];
        qs[r][c] = qv.x; qs[r][c + 1] = qv.y; qs[r][c + 2] = qv.z; qs[r][c + 3] = qv.w;
        ks[r][c] = kv.x; ks[r][c + 1] = kv.y; ks[r][c + 2] = kv.z; ks[r][c + 3] = kv.w;
        if (tid < 32) vs[tid] = 2.0f * v[h0 + tid];
        __syncthreads();
#pragma unroll
        for (int hh = 0; hh < 32; ++hh) {
            float q0 = qs[ty * 2][hh], q1 = qs[ty * 2 + 1][hh];
            float k0 = ks[tx * 2][hh], k1 = ks[tx * 2 + 1][hh];
            float vh = vs[hh];
            float r00 = __builtin_amdgcn_rcpf(exp2f(q0 + k0) + 1.0f);
            float r01 = __builtin_amdgcn_rcpf(exp2f(q0 + k1) + 1.0f);
            float r10 = __builtin_amdgcn_rcpf(exp2f(q1 + k0) + 1.0f);
            float r11 = __builtin_amdgcn_rcpf(exp2f(q1 + k1) + 1.0f);
            acc[0][0] = fmaf(-vh, r00, acc[0][0]);
            acc[0][1] = fmaf(-vh, r01, acc[0][1]);
            acc[1][0] = fmaf(-vh, r10, acc[1][0]);
            acc[1][1] = fmaf(-vh, r11, acc[1][1]);
        }
        __syncthreads();
    }
#pragma unroll
    for (int i = 0; i < 2; ++i) {
        int row = b * T + tbase + ty * 2 + i;
        *(float2*)&score[(size_t)row * S + sbase + tx * 2] =
            make_float2(acc[i][0], acc[i][1]);
    }
}

// per-row masked softmax in place; one wave per row, 8 elems/lane
__global__ __launch_bounds__(64) void softmax_row(
    float* __restrict__ score, const int* __restrict__ slen) {
    const int row = blockIdx.x;
    const int L = slen[row >> 7];   // T = 128
    const int lane = threadIdx.x;
    float* p = score + (size_t)row * S + lane * 8;
    float4 a = *(float4*)p;
    float4 c = *(float4*)(p + 4);
    float x[8] = {a.x, a.y, a.z, a.w, c.x, c.y, c.z, c.w};
    const int s0 = lane * 8;
#pragma unroll
    for (int i = 0; i < 8; ++i)
        if (s0 + i >= L) x[i] = -INFINITY;
    float m = x[0];
#pragma unroll
    for (int i = 1; i < 8; ++i) m = fmaxf(m, x[i]);
#pragma unroll
    for (int off = 1; off < 64; off <<= 1)
        m = fmaxf(m, __shfl_xor(m, off));
    float e[8], sum = 0.f;
#pragma unroll
    for (int i = 0; i < 8; ++i) {
        e[i] = exp2f((x[i] - m) * 1.44269504f);   // masked -> exp2(-inf)=0
        sum += e[i];
    }
#pragma unroll
    for (int off = 1; off < 64; off <<= 1)
        sum += __shfl_xor(sum, off);
    float inv = 1.0f / sum;
    *(float4*)p       = make_float4(e[0] * inv, e[1] * inv, e[2] * inv, e[3] * inv);
    *(float4*)(p + 4) = make_float4(e[4] * inv, e[5] * inv, e[6] * inv, e[7] * inv);
}

// context[b,t,h] = sum_s attn[b,t,s] * enc[b,s,h]; K-loop capped at ceil(L/16)*16
__global__ __launch_bounds__(256) void gemm_ctx(
    const float* __restrict__ attn, const float* __restrict__ enc,
    const int* __restrict__ slen, float* __restrict__ ctx) {
    const int b = blockIdx.z;
    const int L = slen[b];
    const int Keff = min(S, (L + 15) & ~15);
    __shared__ __align__(16) float As[16][68];
    __shared__ __align__(16) float Bs[16][68];
    const int tid = threadIdx.x;
    const int lk = tid & 15;
    const int lr = tid >> 4;
    const int tx = tid & 15;
    const int ty = tid >> 4;
    const int bm = blockIdx.y * 64;   // t
    const int bn = blockIdx.x * 64;   // h
    float acc[4][4] = {};
    for (int k0 = 0; k0 < Keff; k0 += 16) {
#pragma unroll
        for (int i = 0; i < 4; ++i) {
            As[lk][lr + 16 * i] = attn[(size_t)(b * T + bm + lr + 16 * i) * S + k0 + lk];
            Bs[(tid >> 6) + 4 * i][tid & 63] =
                enc[(size_t)(b * S + k0 + (tid >> 6) + 4 * i) * H + bn + (tid & 63)];
        }
        __syncthreads();
#pragma unroll
        for (int kk = 0; kk < 16; ++kk) {
            float4 av = *(const float4*)&As[kk][ty * 4];
            float4 wv = *(const float4*)&Bs[kk][tx * 4];
            float a[4] = {av.x, av.y, av.z, av.w};
            float w[4] = {wv.x, wv.y, wv.z, wv.w};
#pragma unroll
            for (int i = 0; i < 4; ++i)
#pragma unroll
                for (int j = 0; j < 4; ++j)
                    acc[i][j] = fmaf(a[i], w[j], acc[i][j]);
        }
        __syncthreads();
    }
#pragma unroll
    for (int i = 0; i < 4; ++i)
#pragma unroll
        for (int j = 0; j < 4; ++j)
            ctx[(size_t)(b * T + bm + ty * 4 + i) * H + bn + tx * 4 + j] = acc[i][j];
}

// per-row LayerNorm over H=512; block per row
__global__ __launch_bounds__(256) void ln_out(
    const float* __restrict__ X, const float* __restrict__ gamma,
    const float* __restrict__ beta, float* __restrict__ out) {
    __shared__ float red[8];
    const int r = blockIdx.x;
    const int tid = threadIdx.x;
    const int lane = tid & 63, wv = tid >> 6;
    const float* x = X + (size_t)r * H;
    float x0 = x[tid], x1 = x[tid + 256];
    float s = x0 + x1;
#pragma unroll
    for (int off = 32; off > 0; off >>= 1) s += __shfl_down(s, off);
    if (lane == 0) red[wv] = s;
    __syncthreads();
    float mu = (red[0] + red[1] + red[2] + red[3]) * (1.0f / H);
    float d0 = x0 - mu, d1 = x1 - mu;
    float vsum = d0 * d0 + d1 * d1;
#pragma unroll
    for (int off = 32; off > 0; off >>= 1) vsum += __shfl_down(vsum, off);
    if (lane == 0) red[4 + wv] = vsum;
    __syncthreads();
    float var = (red[4] + red[5] + red[6] + red[7]) * (1.0f / H);
    float inv = rsqrtf(var + 1e-5f);
    out[(size_t)r * H + tid] = d0 * inv * gamma[tid] + beta[tid];
    out[(size_t)r * H + tid + 256] = d1 * inv * gamma[tid + 256] + beta[tid + 256];
}

extern "C" void kernel_launch(void* const* d_in, const int* in_sizes, int n_in,
                              void* d_out, int out_size, void* d_ws, size_t ws_size,
                              hipStream_t stream) {
    const float* query = (const float*)d_in[0];
    const float* enc   = (const float*)d_in[1];
    const int*   slen  = (const int*)d_in[2];
    const float* W_h   = (const float*)d_in[3];
    const float* W_s   = (const float*)d_in[4];
    const float* v     = (const float*)d_in[5];
    const float* W_out = (const float*)d_in[6];
    const float* b_out = (const float*)d_in[7];
    const float* gamma = (const float*)d_in[8];
    const float* beta  = (const float*)d_in[9];
    float* out = (float*)d_out;

    // workspace layout (8 MB total)
    float* qp    = (float*)d_ws;        // 512*512   q_proj * 2log2e
    float* kp    = qp + 512 * 512;      // 2048*512  k_proj * 2log2e
    float* score = kp + 2048 * 512;     // 512*512   score -> attn (in place)
    float* ctx   = score + 512 * 512;   // 512*512   context
    float* pre   = ctx + 512 * 512;     // 512*512   pre-LN output

    dim3 blk(256);
    // q_proj (scaled): M=512 N=512 K=512
    gemm_atn<<<dim3(8, 8), blk, 0, stream>>>(query, query, 512, W_s, nullptr, qp,
                                             512, 512, 512, 0, QK_SCALE);
    // k_proj (scaled): M=2048 N=512 K=512
    gemm_atn<<<dim3(8, 32), blk, 0, stream>>>(enc, enc, 512, W_h, nullptr, kp,
                                              2048, 512, 512, 0, QK_SCALE);
    // score tiles: grid (s-tiles=16, t-tiles=4, b=4)
    score_tile<<<dim3(16, 4, 4), blk, 0, stream>>>(qp, kp, v, slen, score);
    // softmax in place: one wave per (b,t) row
    softmax_row<<<dim3(B * T), dim3(64), 0, stream>>>(score, slen);
    // context: grid (h-tiles=8, t-tiles=2, b=4)
    gemm_ctx<<<dim3(8, 2, 4), blk, 0, stream>>>(score, enc, slen, ctx);
    // out = tanh([ctx|query] @ W_out^T + b): M=512 N=512 K=1024, split at 512
    gemm_atn<<<dim3(8, 8), blk, 0, stream>>>(ctx, query, 512, W_out, b_out, pre,
                                             512, 512, 1024, 1, 1.0f);
    // LayerNorm
    ln_out<<<dim3(B * T), blk, 0, stream>>>(pre, gamma, beta, out);
}

// Round 3
// 140.030 us; speedup vs baseline: 1.5604x; 1.5114x over previous
//
#include <hip/hip_runtime.h>
#include <hip/hip_bf16.h>
#include <math.h>

#define B 4
#define T 128
#define S 512
#define H 512
// 2*log2(e): folds tanh's 2x and e->2 base change into the projection epilogue
#define QK_SCALE 2.8853900817779268f

#if defined(__has_builtin)
#if __has_builtin(__builtin_amdgcn_exp2f)
#define EXP2F(x) __builtin_amdgcn_exp2f(x)
#else
#define EXP2F(x) exp2f(x)
#endif
#else
#define EXP2F(x) exp2f(x)
#endif

__device__ __forceinline__ float fast_tanh(float x) {
    float e = __expf(2.0f * x);
    float r = __builtin_amdgcn_rcpf(e + 1.0f);
    return 1.0f - 2.0f * r;
}

// Fused q_proj/k_proj: rows [0,512) -> qp = (query@W_s^T)*QK_SCALE
//                      rows [512,2560) -> kp = (enc@W_h^T)*QK_SCALE
// 32x32 tile, 2x2 micro, 256 threads, K-chunk 32, k-major LDS.
__global__ __launch_bounds__(256) void proj_gemm(
    const float* __restrict__ query, const float* __restrict__ enc,
    const float* __restrict__ W_s, const float* __restrict__ W_h,
    float* __restrict__ qp, float* __restrict__ kp) {
    const int bm = blockIdx.y * 32;
    const int bn = blockIdx.x * 32;
    const float* A; const float* W; float* C;
    if (bm < 512) { A = query + (size_t)bm * H; W = W_s; C = qp + (size_t)bm * H; }
    else { A = enc + (size_t)(bm - 512) * H; W = W_h; C = kp + (size_t)(bm - 512) * H; }
    __shared__ float As[32][38];   // [k][m], stride 38 keeps float2 reads aligned, 2-way max
    __shared__ float Bs[32][38];   // [k][n]
    const int tid = threadIdx.x;
    const int lr = tid >> 3;          // 0..31 row
    const int lc = (tid & 7) * 4;     // 0..28 k
    const int tx = tid & 15, ty = tid >> 4;
    float acc00 = 0, acc01 = 0, acc10 = 0, acc11 = 0;
    for (int k0 = 0; k0 < H; k0 += 32) {
        float4 a4 = *(const float4*)&A[(size_t)lr * H + k0 + lc];
        float4 w4 = *(const float4*)&W[(size_t)(bn + lr) * H + k0 + lc];
        As[lc + 0][lr] = a4.x; As[lc + 1][lr] = a4.y; As[lc + 2][lr] = a4.z; As[lc + 3][lr] = a4.w;
        Bs[lc + 0][lr] = w4.x; Bs[lc + 1][lr] = w4.y; Bs[lc + 2][lr] = w4.z; Bs[lc + 3][lr] = w4.w;
        __syncthreads();
#pragma unroll
        for (int kk = 0; kk < 32; ++kk) {
            float2 av = *(const float2*)&As[kk][ty * 2];
            float2 bv = *(const float2*)&Bs[kk][tx * 2];
            acc00 = fmaf(av.x, bv.x, acc00);
            acc01 = fmaf(av.x, bv.y, acc01);
            acc10 = fmaf(av.y, bv.x, acc10);
            acc11 = fmaf(av.y, bv.y, acc11);
        }
        __syncthreads();
    }
    *(float2*)&C[(size_t)(ty * 2 + 0) * H + bn + tx * 2] =
        make_float2(acc00 * QK_SCALE, acc01 * QK_SCALE);
    *(float2*)&C[(size_t)(ty * 2 + 1) * H + bn + tx * 2] =
        make_float2(acc10 * QK_SCALE, acc11 * QK_SCALE);
}

// out = tanh([ctx|query] @ W_out^T + b): 32x32 tile, K=1024 split at 512.
__global__ __launch_bounds__(256) void out_gemm(
    const float* __restrict__ ctx, const float* __restrict__ query,
    const float* __restrict__ Wo, const float* __restrict__ bias,
    float* __restrict__ pre) {
    const int bm = blockIdx.y * 32;
    const int bn = blockIdx.x * 32;
    __shared__ float As[32][38];
    __shared__ float Bs[32][38];
    const int tid = threadIdx.x;
    const int lr = tid >> 3, lc = (tid & 7) * 4;
    const int tx = tid & 15, ty = tid >> 4;
    float acc00 = 0, acc01 = 0, acc10 = 0, acc11 = 0;
    for (int k0 = 0; k0 < 2 * H; k0 += 32) {
        const float* Ab = (k0 < H) ? (ctx + (size_t)bm * H + k0)
                                   : (query + (size_t)bm * H + (k0 - H));
        float4 a4 = *(const float4*)&Ab[(size_t)lr * H + lc];
        float4 w4 = *(const float4*)&Wo[(size_t)(bn + lr) * (2 * H) + k0 + lc];
        As[lc + 0][lr] = a4.x; As[lc + 1][lr] = a4.y; As[lc + 2][lr] = a4.z; As[lc + 3][lr] = a4.w;
        Bs[lc + 0][lr] = w4.x; Bs[lc + 1][lr] = w4.y; Bs[lc + 2][lr] = w4.z; Bs[lc + 3][lr] = w4.w;
        __syncthreads();
#pragma unroll
        for (int kk = 0; kk < 32; ++kk) {
            float2 av = *(const float2*)&As[kk][ty * 2];
            float2 bv = *(const float2*)&Bs[kk][tx * 2];
            acc00 = fmaf(av.x, bv.x, acc00);
            acc01 = fmaf(av.x, bv.y, acc01);
            acc10 = fmaf(av.y, bv.x, acc10);
            acc11 = fmaf(av.y, bv.y, acc11);
        }
        __syncthreads();
    }
    float b0 = bias[bn + tx * 2], b1 = bias[bn + tx * 2 + 1];
    *(float2*)&pre[(size_t)(bm + ty * 2 + 0) * H + bn + tx * 2] =
        make_float2(fast_tanh(acc00 + b0), fast_tanh(acc01 + b1));
    *(float2*)&pre[(size_t)(bm + ty * 2 + 1) * H + bn + tx * 2] =
        make_float2(fast_tanh(acc10 + b0), fast_tanh(acc11 + b1));
}

// score'[b,t,s] = -sum_h 2*v[h] * rcp(exp2(qp[t,h]+kp[s,h]) + 1)
// (true score differs by the constant sum(v) -- softmax-invariant)
// One wave per 8t x 8s tile; grid.x covers s-tiles, masked tiles early-out.
__global__ __launch_bounds__(64) void score8x8(
    const float* __restrict__ qp, const float* __restrict__ kp,
    const float* __restrict__ v, const int* __restrict__ slen,
    float* __restrict__ score) {
    const int b = blockIdx.z;
    const int L = slen[b];
    const int sbase = blockIdx.x * 8;
    if (sbase >= L) return;
    const int tbase = blockIdx.y * 8;
    __shared__ float qs[8][36];
    __shared__ float ks[8][36];
    __shared__ float vsh[H];
    const int tid = threadIdx.x;
    {   // vsh = 2*v
        float4 v0 = *(const float4*)&v[tid * 8];
        float4 v1 = *(const float4*)&v[tid * 8 + 4];
        *(float4*)&vsh[tid * 8] = make_float4(2.f * v0.x, 2.f * v0.y, 2.f * v0.z, 2.f * v0.w);
        *(float4*)&vsh[tid * 8 + 4] = make_float4(2.f * v1.x, 2.f * v1.y, 2.f * v1.z, 2.f * v1.w);
    }
    const int lr = tid >> 3, lc = (tid & 7) * 4;
    const int t = tid >> 3, s = tid & 7;
    float acc0 = 0.f, acc1 = 0.f;
    for (int h0 = 0; h0 < H; h0 += 32) {
        *(float4*)&qs[lr][lc] = *(const float4*)&qp[(size_t)(b * T + tbase + lr) * H + h0 + lc];
        *(float4*)&ks[lr][lc] = *(const float4*)&kp[(size_t)(b * S + sbase + lr) * H + h0 + lc];
        __syncthreads();
#pragma unroll
        for (int h4 = 0; h4 < 8; ++h4) {
            float4 q4 = *(const float4*)&qs[t][h4 * 4];
            float4 k4 = *(const float4*)&ks[s][h4 * 4];
            float4 v4 = *(const float4*)&vsh[h0 + h4 * 4];
            float e0 = EXP2F(q4.x + k4.x);
            float e1 = EXP2F(q4.y + k4.y);
            float e2 = EXP2F(q4.z + k4.z);
            float e3 = EXP2F(q4.w + k4.w);
            acc0 = fmaf(-v4.x, __builtin_amdgcn_rcpf(e0 + 1.f), acc0);
            acc1 = fmaf(-v4.y, __builtin_amdgcn_rcpf(e1 + 1.f), acc1);
            acc0 = fmaf(-v4.z, __builtin_amdgcn_rcpf(e2 + 1.f), acc0);
            acc1 = fmaf(-v4.w, __builtin_amdgcn_rcpf(e3 + 1.f), acc1);
        }
        __syncthreads();
    }
    score[(size_t)(b * T + tbase + t) * S + sbase + s] = acc0 + acc1;
}

// per-row masked softmax in place; one wave per row, 8 elems/lane
__global__ __launch_bounds__(64) void softmax_row(
    float* __restrict__ score, const int* __restrict__ slen) {
    const int row = blockIdx.x;
    const int L = slen[row >> 7];   // T = 128
    const int lane = threadIdx.x;
    float* p = score + (size_t)row * S + lane * 8;
    float4 a = *(float4*)p;
    float4 c = *(float4*)(p + 4);
    float x[8] = {a.x, a.y, a.z, a.w, c.x, c.y, c.z, c.w};
    const int s0 = lane * 8;
#pragma unroll
    for (int i = 0; i < 8; ++i)
        if (s0 + i >= L) x[i] = -INFINITY;
    float m = x[0];
#pragma unroll
    for (int i = 1; i < 8; ++i) m = fmaxf(m, x[i]);
#pragma unroll
    for (int off = 1; off < 64; off <<= 1)
        m = fmaxf(m, __shfl_xor(m, off));
    float e[8], sum = 0.f;
#pragma unroll
    for (int i = 0; i < 8; ++i) {
        e[i] = exp2f((x[i] - m) * 1.44269504f);
        sum += e[i];
    }
#pragma unroll
    for (int off = 1; off < 64; off <<= 1)
        sum += __shfl_xor(sum, off);
    float inv = 1.0f / sum;
    *(float4*)p       = make_float4(e[0] * inv, e[1] * inv, e[2] * inv, e[3] * inv);
    *(float4*)(p + 4) = make_float4(e[4] * inv, e[5] * inv, e[6] * inv, e[7] * inv);
}

// context = attn @ enc : 16(t) x 32(h) tile per block, K capped by ceil(L/32)*32
__global__ __launch_bounds__(256) void ctx_gemm(
    const float* __restrict__ attn, const float* __restrict__ enc,
    const int* __restrict__ slen, float* __restrict__ ctx) {
    const int b = blockIdx.z;
    const int L = slen[b];
    const int Keff = min(S, (L + 31) & ~31);
    const int bm = blockIdx.y * 16;   // t
    const int bn = blockIdx.x * 32;   // h
    __shared__ float As[32][20];      // [k][t]
    __shared__ float Bs[32][36];      // [k][h]
    const int tid = threadIdx.x;
    const int ra = tid >> 4, ca = (tid & 15) * 2;
    const int rb = tid >> 3, cb = (tid & 7) * 4;
    const int tx = tid & 15, ty = tid >> 4;
    float acc0 = 0.f, acc1 = 0.f;
    for (int k0 = 0; k0 < Keff; k0 += 32) {
        float2 a2 = *(const float2*)&attn[(size_t)(b * T + bm + ra) * S + k0 + ca];
        As[ca + 0][ra] = a2.x;
        As[ca + 1][ra] = a2.y;
        *(float4*)&Bs[rb][cb] = *(const float4*)&enc[(size_t)(b * S + k0 + rb) * H + bn + cb];
        __syncthreads();
#pragma unroll
        for (int kk = 0; kk < 32; ++kk) {
            float a = As[kk][ty];
            float2 bv = *(const float2*)&Bs[kk][tx * 2];
            acc0 = fmaf(a, bv.x, acc0);
            acc1 = fmaf(a, bv.y, acc1);
        }
        __syncthreads();
    }
    *(float2*)&ctx[(size_t)(b * T + bm + ty) * H + bn + tx * 2] = make_float2(acc0, acc1);
}

// per-row LayerNorm over H=512; block per row
__global__ __launch_bounds__(256) void ln_out(
    const float* __restrict__ X, const float* __restrict__ gamma,
    const float* __restrict__ beta, float* __restrict__ out) {
    __shared__ float red[8];
    const int r = blockIdx.x;
    const int tid = threadIdx.x;
    const int lane = tid & 63, wv = tid >> 6;
    const float* x = X + (size_t)r * H;
    float x0 = x[tid], x1 = x[tid + 256];
    float s = x0 + x1;
#pragma unroll
    for (int off = 32; off > 0; off >>= 1) s += __shfl_down(s, off);
    if (lane == 0) red[wv] = s;
    __syncthreads();
    float mu = (red[0] + red[1] + red[2] + red[3]) * (1.0f / H);
    float d0 = x0 - mu, d1 = x1 - mu;
    float vsum = d0 * d0 + d1 * d1;
#pragma unroll
    for (int off = 32; off > 0; off >>= 1) vsum += __shfl_down(vsum, off);
    if (lane == 0) red[4 + wv] = vsum;
    __syncthreads();
    float var = (red[4] + red[5] + red[6] + red[7]) * (1.0f / H);
    float inv = rsqrtf(var + 1e-5f);
    out[(size_t)r * H + tid] = d0 * inv * gamma[tid] + beta[tid];
    out[(size_t)r * H + tid + 256] = d1 * inv * gamma[tid + 256] + beta[tid + 256];
}

extern "C" void kernel_launch(void* const* d_in, const int* in_sizes, int n_in,
                              void* d_out, int out_size, void* d_ws, size_t ws_size,
                              hipStream_t stream) {
    const float* query = (const float*)d_in[0];
    const float* enc   = (const float*)d_in[1];
    const int*   slen  = (const int*)d_in[2];
    const float* W_h   = (const float*)d_in[3];
    const float* W_s   = (const float*)d_in[4];
    const float* v     = (const float*)d_in[5];
    const float* W_out = (const float*)d_in[6];
    const float* b_out = (const float*)d_in[7];
    const float* gamma = (const float*)d_in[8];
    const float* beta  = (const float*)d_in[9];
    float* out = (float*)d_out;

    // workspace (8 MB)
    float* qp    = (float*)d_ws;        // 512*512
    float* kp    = qp + 512 * 512;      // 2048*512
    float* score = kp + 2048 * 512;     // 512*512 (score -> attn in place)
    float* ctx   = score + 512 * 512;   // 512*512
    float* pre   = ctx + 512 * 512;     // 512*512

    // fused projections: M = 512 + 2048 rows of 32 -> 80 tiles
    proj_gemm<<<dim3(16, 80), dim3(256), 0, stream>>>(query, enc, W_s, W_h, qp, kp);
    // score tiles: 1 wave per 8x8 tile
    score8x8<<<dim3(64, 16, 4), dim3(64), 0, stream>>>(qp, kp, v, slen, score);
    softmax_row<<<dim3(B * T), dim3(64), 0, stream>>>(score, slen);
    ctx_gemm<<<dim3(16, 8, 4), dim3(256), 0, stream>>>(score, enc, slen, ctx);
    out_gemm<<<dim3(16, 16), dim3(256), 0, stream>>>(ctx, query, W_out, b_out, pre);
    ln_out<<<dim3(B * T), dim3(256), 0, stream>>>(pre, gamma, beta, out);
}

// Round 4
// 96.231 us; speedup vs baseline: 2.2706x; 1.4551x over previous
//
#include <hip/hip_runtime.h>
#include <hip/hip_bf16.h>
#include <math.h>

#define B 4
#define T 128
#define S 512
#define H 512
// 2*log2(e): folds tanh's 2x and e->2 base change into the projection epilogue
#define QK_SCALE 2.8853900817779268f

typedef __attribute__((ext_vector_type(8))) short bf16x8;
typedef __attribute__((ext_vector_type(4))) float f32x4;

__device__ __forceinline__ short f2b(float x) {   // f32 -> bf16 RNE
    unsigned int u = __float_as_uint(x);
    u += 0x7fffu + ((u >> 16) & 1u);
    return (short)(u >> 16);
}
__device__ __forceinline__ float b2f(unsigned short u) {  // exact
    return __uint_as_float((unsigned int)u << 16);
}
__device__ __forceinline__ float fast_tanh(float x) {
    float e = __expf(2.0f * x);
    float r = __builtin_amdgcn_rcpf(e + 1.0f);
    return 1.0f - 2.0f * r;
}

// ---- phase 1: convert query/W_s/W_h/W_out/enc to bf16 ----
// concat element ranges: q[0,262144) Ws[..524288) Wh[..786432) Wo[..1310720) enc[..2359296)
__global__ __launch_bounds__(256) void cvt_all(
    const float* __restrict__ q, const float* __restrict__ Ws,
    const float* __restrict__ Wh, const float* __restrict__ Wo,
    const float* __restrict__ enc,
    short* __restrict__ qb, short* __restrict__ wsb, short* __restrict__ whb,
    short* __restrict__ wob, short* __restrict__ eb) {
    size_t i = ((size_t)blockIdx.x * 256 + threadIdx.x) * 8;
    const float* src; short* dst; size_t off;
    if (i < 262144)        { src = q;   dst = qb;  off = i; }
    else if (i < 524288)   { src = Ws;  dst = wsb; off = i - 262144; }
    else if (i < 786432)   { src = Wh;  dst = whb; off = i - 524288; }
    else if (i < 1310720)  { src = Wo;  dst = wob; off = i - 786432; }
    else                   { src = enc; dst = eb;  off = i - 1310720; }
    float4 a = *(const float4*)(src + off);
    float4 b = *(const float4*)(src + off + 4);
    ushort4 o0 = make_ushort4((unsigned short)f2b(a.x), (unsigned short)f2b(a.y),
                              (unsigned short)f2b(a.z), (unsigned short)f2b(a.w));
    ushort4 o1 = make_ushort4((unsigned short)f2b(b.x), (unsigned short)f2b(b.y),
                              (unsigned short)f2b(b.z), (unsigned short)f2b(b.w));
    *(ushort4*)(dst + off) = o0;
    *(ushort4*)(dst + off + 4) = o1;
}

// ---- phase 5: encT[b][h][s] = bf16(enc[b][s][h]) ----
__global__ __launch_bounds__(256) void enc_transpose(
    const float* __restrict__ enc, short* __restrict__ encT) {
    const int b = blockIdx.z, s0 = blockIdx.y * 32, h0 = blockIdx.x * 32;
    __shared__ short t[32][33];
    const int r = threadIdx.x >> 3, c = (threadIdx.x & 7) * 4;
    float4 a = *(const float4*)&enc[((size_t)(b * S + s0 + r)) * H + h0 + c];
    t[c + 0][r] = f2b(a.x); t[c + 1][r] = f2b(a.y);
    t[c + 2][r] = f2b(a.z); t[c + 3][r] = f2b(a.w);
    __syncthreads();
    ushort4 o = make_ushort4((unsigned short)t[r][c], (unsigned short)t[r][c + 1],
                             (unsigned short)t[r][c + 2], (unsigned short)t[r][c + 3]);
    *(ushort4*)&encT[((size_t)(b * H + h0 + r)) * S + s0 + c] = o;
}

// ---- MFMA wave-GEMM core: 32x32 per wave, direct global loads ----
// A-frag: lane holds A[(lane&15)][ (lane>>4)*8 + 0..7 ]  (16B contiguous)
// C-frag: col = lane&15, row = (lane>>4)*4 + reg
#define MFMA4(APTR0, APTR1, BPTR0, BPTR1, KOFF)                                  \
    {                                                                            \
        bf16x8 a0 = *(const bf16x8*)((APTR0) + (KOFF));                          \
        bf16x8 a1 = *(const bf16x8*)((APTR1) + (KOFF));                          \
        bf16x8 b0 = *(const bf16x8*)((BPTR0) + (KOFF));                          \
        bf16x8 b1 = *(const bf16x8*)((BPTR1) + (KOFF));                          \
        acc00 = __builtin_amdgcn_mfma_f32_16x16x32_bf16(a0, b0, acc00, 0, 0, 0); \
        acc01 = __builtin_amdgcn_mfma_f32_16x16x32_bf16(a0, b1, acc01, 0, 0, 0); \
        acc10 = __builtin_amdgcn_mfma_f32_16x16x32_bf16(a1, b0, acc10, 0, 0, 0); \
        acc11 = __builtin_amdgcn_mfma_f32_16x16x32_bf16(a1, b1, acc11, 0, 0, 0); \
    }

// ---- phase 2: fused projections, qp/kp = bf16(GEMM * QK_SCALE) ----
__global__ __launch_bounds__(64) void mfma_proj(
    const short* __restrict__ qb, const short* __restrict__ eb,
    const short* __restrict__ wsb, const short* __restrict__ whb,
    short* __restrict__ qp, short* __restrict__ kp) {
    const int lane = threadIdx.x;
    const int r = lane & 15, kb = lane >> 4;
    const int n0 = blockIdx.x * 32;
    const int m0 = blockIdx.y * 32;
    const short* A; const short* W; short* C;
    if (m0 < 512) { A = qb + (size_t)m0 * H; W = wsb; C = qp + (size_t)m0 * H; }
    else { A = eb + (size_t)(m0 - 512) * H; W = whb; C = kp + (size_t)(m0 - 512) * H; }
    const short* a0p = A + (size_t)r * H + kb * 8;
    const short* a1p = a0p + 16 * H;
    const short* b0p = W + (size_t)(n0 + r) * H + kb * 8;
    const short* b1p = b0p + 16 * H;
    f32x4 acc00 = {0,0,0,0}, acc01 = {0,0,0,0}, acc10 = {0,0,0,0}, acc11 = {0,0,0,0};
#pragma unroll 4
    for (int k = 0; k < H; k += 32) MFMA4(a0p, a1p, b0p, b1p, k)
    const int cr = kb * 4, cc = r;
#pragma unroll
    for (int g = 0; g < 4; ++g) {
        C[(size_t)(cr + g) * H + n0 + cc]           = f2b(acc00[g] * QK_SCALE);
        C[(size_t)(cr + g) * H + n0 + 16 + cc]      = f2b(acc01[g] * QK_SCALE);
        C[(size_t)(16 + cr + g) * H + n0 + cc]      = f2b(acc10[g] * QK_SCALE);
        C[(size_t)(16 + cr + g) * H + n0 + 16 + cc] = f2b(acc11[g] * QK_SCALE);
    }
}

// ---- phase 3: score'[b,t,s] = -sum_h 2 v[h] rcp(exp2(qp+kp)+1) (softmax-shift-equivalent) ----
__global__ __launch_bounds__(64) void score8x8(
    const short* __restrict__ qp, const short* __restrict__ kp,
    const float* __restrict__ v, const int* __restrict__ slen,
    float* __restrict__ score) {
    const int b = blockIdx.z;
    const int L = slen[b];
    const int sbase = blockIdx.x * 8;
    if (sbase >= L) return;
    const int tbase = blockIdx.y * 8;
    __shared__ float qs[8][36];
    __shared__ float ks[8][36];
    __shared__ float vsh[H];
    const int tid = threadIdx.x;
    {
        float4 v0 = *(const float4*)&v[tid * 8];
        float4 v1 = *(const float4*)&v[tid * 8 + 4];
        *(float4*)&vsh[tid * 8]     = make_float4(2.f * v0.x, 2.f * v0.y, 2.f * v0.z, 2.f * v0.w);
        *(float4*)&vsh[tid * 8 + 4] = make_float4(2.f * v1.x, 2.f * v1.y, 2.f * v1.z, 2.f * v1.w);
    }
    const int lr = tid >> 3, lc = (tid & 7) * 4;
    const int t = tid >> 3, s = tid & 7;
    float acc0 = 0.f, acc1 = 0.f;
    for (int h0 = 0; h0 < H; h0 += 32) {
        ushort4 qv = *(const ushort4*)&qp[(size_t)(b * T + tbase + lr) * H + h0 + lc];
        ushort4 kv = *(const ushort4*)&kp[(size_t)(b * S + sbase + lr) * H + h0 + lc];
        qs[lr][lc + 0] = b2f(qv.x); qs[lr][lc + 1] = b2f(qv.y);
        qs[lr][lc + 2] = b2f(qv.z); qs[lr][lc + 3] = b2f(qv.w);
        ks[lr][lc + 0] = b2f(kv.x); ks[lr][lc + 1] = b2f(kv.y);
        ks[lr][lc + 2] = b2f(kv.z); ks[lr][lc + 3] = b2f(kv.w);
        __syncthreads();
#pragma unroll
        for (int h4 = 0; h4 < 8; ++h4) {
            float4 q4 = *(const float4*)&qs[t][h4 * 4];
            float4 k4 = *(const float4*)&ks[s][h4 * 4];
            float4 v4 = *(const float4*)&vsh[h0 + h4 * 4];
            float e0 = exp2f(q4.x + k4.x);
            float e1 = exp2f(q4.y + k4.y);
            float e2 = exp2f(q4.z + k4.z);
            float e3 = exp2f(q4.w + k4.w);
            acc0 = fmaf(-v4.x, __builtin_amdgcn_rcpf(e0 + 1.f), acc0);
            acc1 = fmaf(-v4.y, __builtin_amdgcn_rcpf(e1 + 1.f), acc1);
            acc0 = fmaf(-v4.z, __builtin_amdgcn_rcpf(e2 + 1.f), acc0);
            acc1 = fmaf(-v4.w, __builtin_amdgcn_rcpf(e3 + 1.f), acc1);
        }
        __syncthreads();
    }
    score[(size_t)(b * T + tbase + t) * S + sbase + s] = acc0 + acc1;
}

// ---- phase 4: per-row masked softmax, writes bf16 attn ----
__global__ __launch_bounds__(64) void softmax_row(
    const float* __restrict__ score, const int* __restrict__ slen,
    short* __restrict__ attnb) {
    const int row = blockIdx.x;
    const int L = slen[row >> 7];
    const int lane = threadIdx.x;
    const float* p = score + (size_t)row * S + lane * 8;
    float4 a = *(const float4*)p;
    float4 c = *(const float4*)(p + 4);
    float x[8] = {a.x, a.y, a.z, a.w, c.x, c.y, c.z, c.w};
    const int s0 = lane * 8;
#pragma unroll
    for (int i = 0; i < 8; ++i)
        if (s0 + i >= L) x[i] = -INFINITY;
    float m = x[0];
#pragma unroll
    for (int i = 1; i < 8; ++i) m = fmaxf(m, x[i]);
#pragma unroll
    for (int off = 1; off < 64; off <<= 1)
        m = fmaxf(m, __shfl_xor(m, off));
    float e[8], sum = 0.f;
#pragma unroll
    for (int i = 0; i < 8; ++i) {
        e[i] = exp2f((x[i] - m) * 1.44269504f);
        sum += e[i];
    }
#pragma unroll
    for (int off = 1; off < 64; off <<= 1)
        sum += __shfl_xor(sum, off);
    float inv = 1.0f / sum;
    short* o = attnb + (size_t)row * S + lane * 8;
    ushort4 o0 = make_ushort4((unsigned short)f2b(e[0] * inv), (unsigned short)f2b(e[1] * inv),
                              (unsigned short)f2b(e[2] * inv), (unsigned short)f2b(e[3] * inv));
    ushort4 o1 = make_ushort4((unsigned short)f2b(e[4] * inv), (unsigned short)f2b(e[5] * inv),
                              (unsigned short)f2b(e[6] * inv), (unsigned short)f2b(e[7] * inv));
    *(ushort4*)o = o0;
    *(ushort4*)(o + 4) = o1;
}

// ---- phase 6: ctx = attn @ enc (K capped at ceil(L/32)*32; masked attn == 0) ----
__global__ __launch_bounds__(64) void mfma_ctx(
    const short* __restrict__ attnb, const short* __restrict__ encT,
    const int* __restrict__ slen, short* __restrict__ ctxb) {
    const int b = blockIdx.z;
    const int L = slen[b];
    const int Keff = min(S, (L + 31) & ~31);
    const int lane = threadIdx.x;
    const int r = lane & 15, kb = lane >> 4;
    const int m0 = blockIdx.y * 32;
    const int n0 = blockIdx.x * 32;
    const short* A = attnb + (size_t)(b * T + m0) * S;
    const short* Bp = encT + (size_t)b * H * S;
    const short* a0p = A + (size_t)r * S + kb * 8;
    const short* a1p = a0p + 16 * S;
    const short* b0p = Bp + (size_t)(n0 + r) * S + kb * 8;
    const short* b1p = b0p + 16 * S;
    f32x4 acc00 = {0,0,0,0}, acc01 = {0,0,0,0}, acc10 = {0,0,0,0}, acc11 = {0,0,0,0};
#pragma unroll 2
    for (int k = 0; k < Keff; k += 32) MFMA4(a0p, a1p, b0p, b1p, k)
    const int cr = kb * 4, cc = r;
#pragma unroll
    for (int g = 0; g < 4; ++g) {
        size_t row0 = (size_t)(b * T + m0 + cr + g) * H;
        size_t row1 = (size_t)(b * T + m0 + 16 + cr + g) * H;
        ctxb[row0 + n0 + cc]      = f2b(acc00[g]);
        ctxb[row0 + n0 + 16 + cc] = f2b(acc01[g]);
        ctxb[row1 + n0 + cc]      = f2b(acc10[g]);
        ctxb[row1 + n0 + 16 + cc] = f2b(acc11[g]);
    }
}

// ---- phase 7: pre = tanh([ctx|query] @ W_out^T + b) ----
__global__ __launch_bounds__(64) void mfma_out(
    const short* __restrict__ ctxb, const short* __restrict__ qb,
    const short* __restrict__ wob, const float* __restrict__ bias,
    float* __restrict__ pre) {
    const int lane = threadIdx.x;
    const int r = lane & 15, kb = lane >> 4;
    const int m0 = blockIdx.y * 32, n0 = blockIdx.x * 32;
    f32x4 acc00 = {0,0,0,0}, acc01 = {0,0,0,0}, acc10 = {0,0,0,0}, acc11 = {0,0,0,0};
    const short* b0p = wob + (size_t)(n0 + r) * (2 * H) + kb * 8;
    const short* b1p = b0p + 16 * (2 * H);
    {
        const short* a0p = ctxb + (size_t)(m0 + r) * H + kb * 8;
        const short* a1p = a0p + 16 * H;
#pragma unroll 4
        for (int k = 0; k < H; k += 32) MFMA4(a0p, a1p, b0p, b1p, k)
    }
    {
        const short* a0p = qb + (size_t)(m0 + r) * H + kb * 8;
        const short* a1p = a0p + 16 * H;
        const short* c0p = b0p + H;
        const short* c1p = b1p + H;
#pragma unroll 4
        for (int k = 0; k < H; k += 32) MFMA4(a0p, a1p, c0p, c1p, k)
    }
    const int cr = kb * 4, cc = r;
    float bn0 = bias[n0 + cc], bn1 = bias[n0 + 16 + cc];
#pragma unroll
    for (int g = 0; g < 4; ++g) {
        size_t row0 = (size_t)(m0 + cr + g) * H;
        size_t row1 = (size_t)(m0 + 16 + cr + g) * H;
        pre[row0 + n0 + cc]      = fast_tanh(acc00[g] + bn0);
        pre[row0 + n0 + 16 + cc] = fast_tanh(acc01[g] + bn1);
        pre[row1 + n0 + cc]      = fast_tanh(acc10[g] + bn0);
        pre[row1 + n0 + 16 + cc] = fast_tanh(acc11[g] + bn1);
    }
}

// ---- phase 8: per-row LayerNorm ----
__global__ __launch_bounds__(256) void ln_out(
    const float* __restrict__ X, const float* __restrict__ gamma,
    const float* __restrict__ beta, float* __restrict__ out) {
    __shared__ float red[8];
    const int r = blockIdx.x;
    const int tid = threadIdx.x;
    const int lane = tid & 63, wv = tid >> 6;
    const float* x = X + (size_t)r * H;
    float x0 = x[tid], x1 = x[tid + 256];
    float s = x0 + x1;
#pragma unroll
    for (int off = 32; off > 0; off >>= 1) s += __shfl_down(s, off);
    if (lane == 0) red[wv] = s;
    __syncthreads();
    float mu = (red[0] + red[1] + red[2] + red[3]) * (1.0f / H);
    float d0 = x0 - mu, d1 = x1 - mu;
    float vsum = d0 * d0 + d1 * d1;
#pragma unroll
    for (int off = 32; off > 0; off >>= 1) vsum += __shfl_down(vsum, off);
    if (lane == 0) red[4 + wv] = vsum;
    __syncthreads();
    float var = (red[4] + red[5] + red[6] + red[7]) * (1.0f / H);
    float inv = rsqrtf(var + 1e-5f);
    out[(size_t)r * H + tid] = d0 * inv * gamma[tid] + beta[tid];
    out[(size_t)r * H + tid + 256] = d1 * inv * gamma[tid + 256] + beta[tid + 256];
}

extern "C" void kernel_launch(void* const* d_in, const int* in_sizes, int n_in,
                              void* d_out, int out_size, void* d_ws, size_t ws_size,
                              hipStream_t stream) {
    const float* query = (const float*)d_in[0];
    const float* enc   = (const float*)d_in[1];
    const int*   slen  = (const int*)d_in[2];
    const float* W_h   = (const float*)d_in[3];
    const float* W_s   = (const float*)d_in[4];
    const float* v     = (const float*)d_in[5];
    const float* W_out = (const float*)d_in[6];
    const float* b_out = (const float*)d_in[7];
    const float* gamma = (const float*)d_in[8];
    const float* beta  = (const float*)d_in[9];
    float* out = (float*)d_out;

    // ---- aliased workspace map (peak 7.0 MB; ws_size >= 8 MB proven in R1-R3) ----
    char* base = (char*)d_ws;
    short* qb    = (short*)(base + 0);        // 512KB  bf16 query      [ph1..7]
    short* wsb   = (short*)(base + 524288);   // 512KB  bf16 W_s        [ph1..2]
    short* ctxb  = (short*)(base + 524288);   //   -> bf16 ctx          [ph6..7]
    short* whb   = (short*)(base + 1048576);  // 512KB  bf16 W_h        [ph1..2]
    short* attnb = (short*)(base + 1048576);  //   -> bf16 attn         [ph4..6]
    short* eb    = (short*)(base + 1572864);  // 2MB    bf16 enc        [ph1..2]
    float* score = (float*)(base + 1572864);  //   -> f32 score (1MB)   [ph3..4]
    float* pre   = (float*)(base + 1572864);  //   -> f32 pre-LN (1MB)  [ph7..8]
    short* qp    = (short*)(base + 3670016);  // 512KB  bf16 q_proj     [ph2..3]
    short* kp    = (short*)(base + 4194304);  // 2MB    bf16 k_proj     [ph2..3]
    short* encT  = (short*)(base + 4194304);  //   -> bf16 enc^T        [ph5..6]
    short* wob   = (short*)(base + 6291456);  // 1MB    bf16 W_out      [ph1..7]

    cvt_all<<<dim3(1152), dim3(256), 0, stream>>>(query, W_s, W_h, W_out, enc,
                                                  qb, wsb, whb, wob, eb);
    mfma_proj<<<dim3(16, 80), dim3(64), 0, stream>>>(qb, eb, wsb, whb, qp, kp);
    score8x8<<<dim3(64, 16, 4), dim3(64), 0, stream>>>(qp, kp, v, slen, score);
    softmax_row<<<dim3(B * T), dim3(64), 0, stream>>>(score, slen, attnb);
    enc_transpose<<<dim3(16, 16, 4), dim3(256), 0, stream>>>(enc, encT);
    mfma_ctx<<<dim3(16, 4, 4), dim3(64), 0, stream>>>(attnb, encT, slen, ctxb);
    mfma_out<<<dim3(16, 16), dim3(64), 0, stream>>>(ctxb, qb, wob, b_out, pre);
    ln_out<<<dim3(B * T), dim3(256), 0, stream>>>(pre, gamma, beta, out);
}

// Round 5
// 95.443 us; speedup vs baseline: 2.2894x; 1.0083x over previous
//
#include <hip/hip_runtime.h>
#include <hip/hip_bf16.h>
#include <math.h>

#define B 4
#define T 128
#define S 512
#define H 512
// 2*log2(e): folds tanh's 2x and e->2 base change into the projection epilogue
#define QK_SCALE 2.8853900817779268f

typedef __attribute__((ext_vector_type(8))) short bf16x8;
typedef __attribute__((ext_vector_type(4))) float f32x4;

__device__ __forceinline__ short f2b(float x) {   // f32 -> bf16 RNE
    unsigned int u = __float_as_uint(x);
    u += 0x7fffu + ((u >> 16) & 1u);
    return (short)(u >> 16);
}
__device__ __forceinline__ float blo(unsigned int u) {  // low bf16 -> f32
    return __uint_as_float(u << 16);
}
__device__ __forceinline__ float bhi(unsigned int u) {  // high bf16 -> f32
    return __uint_as_float(u & 0xffff0000u);
}
__device__ __forceinline__ float fast_tanh(float x) {
    float e = __expf(2.0f * x);
    float r = __builtin_amdgcn_rcpf(e + 1.0f);
    return 1.0f - 2.0f * r;
}

// ---- phase 1: convert query/W_s/W_h/W_out/enc to bf16 ----
__global__ __launch_bounds__(256) void cvt_all(
    const float* __restrict__ q, const float* __restrict__ Ws,
    const float* __restrict__ Wh, const float* __restrict__ Wo,
    const float* __restrict__ enc,
    short* __restrict__ qb, short* __restrict__ wsb, short* __restrict__ whb,
    short* __restrict__ wob, short* __restrict__ eb) {
    size_t i = ((size_t)blockIdx.x * 256 + threadIdx.x) * 8;
    const float* src; short* dst; size_t off;
    if (i < 262144)        { src = q;   dst = qb;  off = i; }
    else if (i < 524288)   { src = Ws;  dst = wsb; off = i - 262144; }
    else if (i < 786432)   { src = Wh;  dst = whb; off = i - 524288; }
    else if (i < 1310720)  { src = Wo;  dst = wob; off = i - 786432; }
    else                   { src = enc; dst = eb;  off = i - 1310720; }
    float4 a = *(const float4*)(src + off);
    float4 b = *(const float4*)(src + off + 4);
    ushort4 o0 = make_ushort4((unsigned short)f2b(a.x), (unsigned short)f2b(a.y),
                              (unsigned short)f2b(a.z), (unsigned short)f2b(a.w));
    ushort4 o1 = make_ushort4((unsigned short)f2b(b.x), (unsigned short)f2b(b.y),
                              (unsigned short)f2b(b.z), (unsigned short)f2b(b.w));
    *(ushort4*)(dst + off) = o0;
    *(ushort4*)(dst + off + 4) = o1;
}

// ---- MFMA wave-GEMM core: 32x32 per wave, direct global loads ----
#define MFMA4(APTR0, APTR1, BPTR0, BPTR1, KOFF)                                  \
    {                                                                            \
        bf16x8 a0 = *(const bf16x8*)((APTR0) + (KOFF));                          \
        bf16x8 a1 = *(const bf16x8*)((APTR1) + (KOFF));                          \
        bf16x8 b0 = *(const bf16x8*)((BPTR0) + (KOFF));                          \
        bf16x8 b1 = *(const bf16x8*)((BPTR1) + (KOFF));                          \
        acc00 = __builtin_amdgcn_mfma_f32_16x16x32_bf16(a0, b0, acc00, 0, 0, 0); \
        acc01 = __builtin_amdgcn_mfma_f32_16x16x32_bf16(a0, b1, acc01, 0, 0, 0); \
        acc10 = __builtin_amdgcn_mfma_f32_16x16x32_bf16(a1, b0, acc10, 0, 0, 0); \
        acc11 = __builtin_amdgcn_mfma_f32_16x16x32_bf16(a1, b1, acc11, 0, 0, 0); \
    }

// ---- phase 2: fused projections, qp/kp = bf16(GEMM * QK_SCALE) ----
__global__ __launch_bounds__(64) void mfma_proj(
    const short* __restrict__ qb, const short* __restrict__ eb,
    const short* __restrict__ wsb, const short* __restrict__ whb,
    short* __restrict__ qp, short* __restrict__ kp) {
    const int lane = threadIdx.x;
    const int r = lane & 15, kb = lane >> 4;
    const int n0 = blockIdx.x * 32;
    const int m0 = blockIdx.y * 32;
    const short* A; const short* W; short* C;
    if (m0 < 512) { A = qb + (size_t)m0 * H; W = wsb; C = qp + (size_t)m0 * H; }
    else { A = eb + (size_t)(m0 - 512) * H; W = whb; C = kp + (size_t)(m0 - 512) * H; }
    const short* a0p = A + (size_t)r * H + kb * 8;
    const short* a1p = a0p + 16 * H;
    const short* b0p = W + (size_t)(n0 + r) * H + kb * 8;
    const short* b1p = b0p + 16 * H;
    f32x4 acc00 = {0,0,0,0}, acc01 = {0,0,0,0}, acc10 = {0,0,0,0}, acc11 = {0,0,0,0};
#pragma unroll 4
    for (int k = 0; k < H; k += 32) MFMA4(a0p, a1p, b0p, b1p, k)
    const int cr = kb * 4, cc = r;
#pragma unroll
    for (int g = 0; g < 4; ++g) {
        C[(size_t)(cr + g) * H + n0 + cc]           = f2b(acc00[g] * QK_SCALE);
        C[(size_t)(cr + g) * H + n0 + 16 + cc]      = f2b(acc01[g] * QK_SCALE);
        C[(size_t)(16 + cr + g) * H + n0 + cc]      = f2b(acc10[g] * QK_SCALE);
        C[(size_t)(16 + cr + g) * H + n0 + 16 + cc] = f2b(acc11[g] * QK_SCALE);
    }
}

// ---- phase 3: partial score over one h-half ----
// scoreh[half][b*T+t][s] = -sum_{h in half} 2 v[h] rcp(exp2(qp+kp)+1)
// One wave per 8t x 8s x 256h; whole tile preloaded to LDS, then pure compute.
__global__ __launch_bounds__(64) void score_v2(
    const short* __restrict__ qp, const short* __restrict__ kp,
    const float* __restrict__ v, const int* __restrict__ slen,
    float* __restrict__ scoreh) {
    const int half = blockIdx.z & 1;
    const int b = blockIdx.z >> 1;
    const int L = slen[b];
    const int sbase = blockIdx.x * 8;
    if (sbase >= L) return;
    const int tbase = blockIdx.y * 8;
    const int hbase = half * 256;
    // row stride 264 shorts = 528B -> row r starts at bank 4r: 8 rows spread banks
    __shared__ __align__(16) short qs[8][264];
    __shared__ __align__(16) short ks[8][264];
    __shared__ __align__(16) float vsh[256];
    const int lane = threadIdx.x;
    {   // staging: lane covers row r = lane>>3, 32-short chunk at (lane&7)*32
        const int r = lane >> 3, c = (lane & 7) * 32;
        const short* qsrc = qp + (size_t)(b * T + tbase + r) * H + hbase + c;
        const short* ksrc = kp + (size_t)(b * S + sbase + r) * H + hbase + c;
#pragma unroll
        for (int j = 0; j < 4; ++j) {
            *(bf16x8*)&qs[r][c + j * 8] = *(const bf16x8*)(qsrc + j * 8);
            *(bf16x8*)&ks[r][c + j * 8] = *(const bf16x8*)(ksrc + j * 8);
        }
        float4 vv = *(const float4*)&v[hbase + lane * 4];
        *(float4*)&vsh[lane * 4] =
            make_float4(-2.f * vv.x, -2.f * vv.y, -2.f * vv.z, -2.f * vv.w);
    }
    __syncthreads();
    const int t = lane >> 3, s = lane & 7;
    const unsigned int* qrow = (const unsigned int*)&qs[t][0];
    const unsigned int* krow = (const unsigned int*)&ks[s][0];
    float a0 = 0.f, a1 = 0.f, a2 = 0.f, a3 = 0.f;
#pragma unroll 8
    for (int i = 0; i < 128; i += 2) {   // 4 h-elements per iteration
        uint2 qu = *(const uint2*)&qrow[i];
        uint2 ku = *(const uint2*)&krow[i];
        float4 vv = *(const float4*)&vsh[i * 2];
        float e0 = exp2f(blo(qu.x) + blo(ku.x)) + 1.f;
        float e1 = exp2f(bhi(qu.x) + bhi(ku.x)) + 1.f;
        float e2 = exp2f(blo(qu.y) + blo(ku.y)) + 1.f;
        float e3 = exp2f(bhi(qu.y) + bhi(ku.y)) + 1.f;
        a0 = fmaf(vv.x, __builtin_amdgcn_rcpf(e0), a0);
        a1 = fmaf(vv.y, __builtin_amdgcn_rcpf(e1), a1);
        a2 = fmaf(vv.z, __builtin_amdgcn_rcpf(e2), a2);
        a3 = fmaf(vv.w, __builtin_amdgcn_rcpf(e3), a3);
    }
    scoreh[((size_t)half * (B * T) + b * T + tbase + t) * S + sbase + s] =
        (a0 + a1) + (a2 + a3);
}

// ---- phase 4: fused {enc transpose -> encT bf16} + {softmax(h0+h1) -> attnb bf16} ----
__global__ __launch_bounds__(256) void mid_kernel(
    const float* __restrict__ scoreh, const int* __restrict__ slen,
    short* __restrict__ attnb, const float* __restrict__ enc,
    short* __restrict__ encT) {
    __shared__ short tb[32][33];
    __shared__ float red[8];
    const int bid = blockIdx.x;
    const int tid = threadIdx.x;
    if (bid < 1024) {   // encT[b][h][s] = bf16(enc[b][s][h])
        const int b = bid >> 8, s0 = ((bid >> 4) & 15) * 32, h0 = (bid & 15) * 32;
        const int r = tid >> 3, c = (tid & 7) * 4;
        float4 a = *(const float4*)&enc[((size_t)(b * S + s0 + r)) * H + h0 + c];
        tb[c + 0][r] = f2b(a.x); tb[c + 1][r] = f2b(a.y);
        tb[c + 2][r] = f2b(a.z); tb[c + 3][r] = f2b(a.w);
        __syncthreads();
        ushort4 o = make_ushort4((unsigned short)tb[r][c], (unsigned short)tb[r][c + 1],
                                 (unsigned short)tb[r][c + 2], (unsigned short)tb[r][c + 3]);
        *(ushort4*)&encT[((size_t)(b * H + h0 + r)) * S + s0 + c] = o;
        return;
    }
    const int row = bid - 1024;          // 0..511
    const int L = slen[row >> 7];        // T = 128
    const int lane = tid & 63, wv = tid >> 6;
    const float* p0 = scoreh + (size_t)row * S;
    const float* p1 = p0 + (size_t)(B * T) * S;
    float x0 = p0[tid] + p1[tid];
    float x1 = p0[tid + 256] + p1[tid + 256];
    if (tid >= L) x0 = -INFINITY;
    if (tid + 256 >= L) x1 = -INFINITY;
    float m = fmaxf(x0, x1);
#pragma unroll
    for (int off = 32; off > 0; off >>= 1) m = fmaxf(m, __shfl_xor(m, off));
    if (lane == 0) red[wv] = m;
    __syncthreads();
    m = fmaxf(fmaxf(red[0], red[1]), fmaxf(red[2], red[3]));
    float e0 = exp2f((x0 - m) * 1.44269504f);
    float e1 = exp2f((x1 - m) * 1.44269504f);
    float sm = e0 + e1;
#pragma unroll
    for (int off = 32; off > 0; off >>= 1) sm += __shfl_xor(sm, off);
    if (lane == 0) red[4 + wv] = sm;
    __syncthreads();
    float inv = 1.0f / (red[4] + red[5] + red[6] + red[7]);
    short* o = attnb + (size_t)row * S;
    o[tid] = f2b(e0 * inv);
    o[tid + 256] = f2b(e1 * inv);
}

// ---- phase 5: ctx = attn @ enc (K capped at ceil(L/32)*32; masked attn == 0) ----
__global__ __launch_bounds__(64) void mfma_ctx(
    const short* __restrict__ attnb, const short* __restrict__ encT,
    const int* __restrict__ slen, short* __restrict__ ctxb) {
    const int b = blockIdx.z;
    const int L = slen[b];
    const int Keff = min(S, (L + 31) & ~31);
    const int lane = threadIdx.x;
    const int r = lane & 15, kb = lane >> 4;
    const int m0 = blockIdx.y * 32;
    const int n0 = blockIdx.x * 32;
    const short* A = attnb + (size_t)(b * T + m0) * S;
    const short* Bp = encT + (size_t)b * H * S;
    const short* a0p = A + (size_t)r * S + kb * 8;
    const short* a1p = a0p + 16 * S;
    const short* b0p = Bp + (size_t)(n0 + r) * S + kb * 8;
    const short* b1p = b0p + 16 * S;
    f32x4 acc00 = {0,0,0,0}, acc01 = {0,0,0,0}, acc10 = {0,0,0,0}, acc11 = {0,0,0,0};
#pragma unroll 2
    for (int k = 0; k < Keff; k += 32) MFMA4(a0p, a1p, b0p, b1p, k)
    const int cr = kb * 4, cc = r;
#pragma unroll
    for (int g = 0; g < 4; ++g) {
        size_t row0 = (size_t)(b * T + m0 + cr + g) * H;
        size_t row1 = (size_t)(b * T + m0 + 16 + cr + g) * H;
        ctxb[row0 + n0 + cc]      = f2b(acc00[g]);
        ctxb[row0 + n0 + 16 + cc] = f2b(acc01[g]);
        ctxb[row1 + n0 + cc]      = f2b(acc10[g]);
        ctxb[row1 + n0 + 16 + cc] = f2b(acc11[g]);
    }
}

// ---- phase 6: pre = tanh([ctx|query] @ W_out^T + b) ----
__global__ __launch_bounds__(64) void mfma_out(
    const short* __restrict__ ctxb, const short* __restrict__ qb,
    const short* __restrict__ wob, const float* __restrict__ bias,
    float* __restrict__ pre) {
    const int lane = threadIdx.x;
    const int r = lane & 15, kb = lane >> 4;
    const int m0 = blockIdx.y * 32, n0 = blockIdx.x * 32;
    f32x4 acc00 = {0,0,0,0}, acc01 = {0,0,0,0}, acc10 = {0,0,0,0}, acc11 = {0,0,0,0};
    const short* b0p = wob + (size_t)(n0 + r) * (2 * H) + kb * 8;
    const short* b1p = b0p + 16 * (2 * H);
    {
        const short* a0p = ctxb + (size_t)(m0 + r) * H + kb * 8;
        const short* a1p = a0p + 16 * H;
#pragma unroll 4
        for (int k = 0; k < H; k += 32) MFMA4(a0p, a1p, b0p, b1p, k)
    }
    {
        const short* a0p = qb + (size_t)(m0 + r) * H + kb * 8;
        const short* a1p = a0p + 16 * H;
        const short* c0p = b0p + H;
        const short* c1p = b1p + H;
#pragma unroll 4
        for (int k = 0; k < H; k += 32) MFMA4(a0p, a1p, c0p, c1p, k)
    }
    const int cr = kb * 4, cc = r;
    float bn0 = bias[n0 + cc], bn1 = bias[n0 + 16 + cc];
#pragma unroll
    for (int g = 0; g < 4; ++g) {
        size_t row0 = (size_t)(m0 + cr + g) * H;
        size_t row1 = (size_t)(m0 + 16 + cr + g) * H;
        pre[row0 + n0 + cc]      = fast_tanh(acc00[g] + bn0);
        pre[row0 + n0 + 16 + cc] = fast_tanh(acc01[g] + bn1);
        pre[row1 + n0 + cc]      = fast_tanh(acc10[g] + bn0);
        pre[row1 + n0 + 16 + cc] = fast_tanh(acc11[g] + bn1);
    }
}

// ---- phase 7: per-row LayerNorm ----
__global__ __launch_bounds__(256) void ln_out(
    const float* __restrict__ X, const float* __restrict__ gamma,
    const float* __restrict__ beta, float* __restrict__ out) {
    __shared__ float red[8];
    const int r = blockIdx.x;
    const int tid = threadIdx.x;
    const int lane = tid & 63, wv = tid >> 6;
    const float* x = X + (size_t)r * H;
    float x0 = x[tid], x1 = x[tid + 256];
    float s = x0 + x1;
#pragma unroll
    for (int off = 32; off > 0; off >>= 1) s += __shfl_down(s, off);
    if (lane == 0) red[wv] = s;
    __syncthreads();
    float mu = (red[0] + red[1] + red[2] + red[3]) * (1.0f / H);
    float d0 = x0 - mu, d1 = x1 - mu;
    float vsum = d0 * d0 + d1 * d1;
#pragma unroll
    for (int off = 32; off > 0; off >>= 1) vsum += __shfl_down(vsum, off);
    if (lane == 0) red[4 + wv] = vsum;
    __syncthreads();
    float var = (red[4] + red[5] + red[6] + red[7]) * (1.0f / H);
    float inv = rsqrtf(var + 1e-5f);
    out[(size_t)r * H + tid] = d0 * inv * gamma[tid] + beta[tid];
    out[(size_t)r * H + tid + 256] = d1 * inv * gamma[tid + 256] + beta[tid + 256];
}

extern "C" void kernel_launch(void* const* d_in, const int* in_sizes, int n_in,
                              void* d_out, int out_size, void* d_ws, size_t ws_size,
                              hipStream_t stream) {
    const float* query = (const float*)d_in[0];
    const float* enc   = (const float*)d_in[1];
    const int*   slen  = (const int*)d_in[2];
    const float* W_h   = (const float*)d_in[3];
    const float* W_s   = (const float*)d_in[4];
    const float* v     = (const float*)d_in[5];
    const float* W_out = (const float*)d_in[6];
    const float* b_out = (const float*)d_in[7];
    const float* gamma = (const float*)d_in[8];
    const float* beta  = (const float*)d_in[9];
    float* out = (float*)d_out;

    // ---- aliased workspace map (peak 7.0 MB) ----
    char* base = (char*)d_ws;
    short* qb     = (short*)(base + 0);        // 512KB  bf16 query    [1..6]
    short* wsb    = (short*)(base + 524288);   // 512KB  W_s           [1..2]
    short* ctxb   = (short*)(base + 524288);   //   -> bf16 ctx        [5..6]
    short* whb    = (short*)(base + 1048576);  // 512KB  W_h           [1..2]
    short* attnb  = (short*)(base + 1048576);  //   -> bf16 attn       [4..5]
    short* eb     = (short*)(base + 1572864);  // 2MB    bf16 enc      [1..2]
    float* scoreh = (float*)(base + 1572864);  //   -> f32 score[2]    [3..4]
    float* pre    = (float*)(base + 1572864);  //   -> f32 pre-LN      [6..7]
    short* qp     = (short*)(base + 3670016);  // 512KB  bf16 q_proj   [2..3]
    short* kp     = (short*)(base + 4194304);  // 2MB    bf16 k_proj   [2..3]
    short* encT   = (short*)(base + 4194304);  //   -> bf16 enc^T      [4..5]
    short* wob    = (short*)(base + 6291456);  // 1MB    bf16 W_out    [1..6]

    cvt_all<<<dim3(1152), dim3(256), 0, stream>>>(query, W_s, W_h, W_out, enc,
                                                  qb, wsb, whb, wob, eb);
    mfma_proj<<<dim3(16, 80), dim3(64), 0, stream>>>(qb, eb, wsb, whb, qp, kp);
    // score halves: grid (s-tiles=64, t-tiles=16, b*2 halves=8)
    score_v2<<<dim3(64, 16, 8), dim3(64), 0, stream>>>(qp, kp, v, slen, scoreh);
    // fused encT (blocks 0..1023) + softmax (blocks 1024..1535)
    mid_kernel<<<dim3(1536), dim3(256), 0, stream>>>(scoreh, slen, attnb, enc, encT);
    mfma_ctx<<<dim3(16, 4, 4), dim3(64), 0, stream>>>(attnb, encT, slen, ctxb);
    mfma_out<<<dim3(16, 16), dim3(64), 0, stream>>>(ctxb, qb, wob, b_out, pre);
    ln_out<<<dim3(B * T), dim3(256), 0, stream>>>(pre, gamma, beta, out);
}

// Round 6
// 81.119 us; speedup vs baseline: 2.6936x; 1.1766x over previous
//
#include <hip/hip_runtime.h>
#include <hip/hip_bf16.h>
#include <math.h>

#define B 4
#define T 128
#define S 512
#define H 512
// 2*log2(e): folds tanh's 2x and e->2 base change into the projection epilogue
#define QK_SCALE 2.8853900817779268f

// Hardware exp2 (v_exp_f32). Fallback stays on the native-exp path
// (__expf = 1 mul + v_exp), NEVER the precise OCML polynomial.
#if defined(__has_builtin)
#if __has_builtin(__builtin_amdgcn_exp2f)
#define EXP2F(x) __builtin_amdgcn_exp2f(x)
#else
#define EXP2F(x) __expf((x) * 0.6931471805599453f)
#endif
#else
#define EXP2F(x) __expf((x) * 0.6931471805599453f)
#endif

typedef __attribute__((ext_vector_type(8))) short bf16x8;
typedef __attribute__((ext_vector_type(4))) float f32x4;

__device__ __forceinline__ short f2b(float x) {   // f32 -> bf16 RNE
    unsigned int u = __float_as_uint(x);
    u += 0x7fffu + ((u >> 16) & 1u);
    return (short)(u >> 16);
}
__device__ __forceinline__ float blo(unsigned int u) {  // low bf16 -> f32
    return __uint_as_float(u << 16);
}
__device__ __forceinline__ float bhi(unsigned int u) {  // high bf16 -> f32
    return __uint_as_float(u & 0xffff0000u);
}
__device__ __forceinline__ float fast_tanh(float x) {
    float e = __expf(2.0f * x);
    float r = __builtin_amdgcn_rcpf(e + 1.0f);
    return 1.0f - 2.0f * r;
}

// ---- phase 1: convert query/W_s/W_h/W_out/enc to bf16 ----
__global__ __launch_bounds__(256) void cvt_all(
    const float* __restrict__ q, const float* __restrict__ Ws,
    const float* __restrict__ Wh, const float* __restrict__ Wo,
    const float* __restrict__ enc,
    short* __restrict__ qb, short* __restrict__ wsb, short* __restrict__ whb,
    short* __restrict__ wob, short* __restrict__ eb) {
    size_t i = ((size_t)blockIdx.x * 256 + threadIdx.x) * 8;
    const float* src; short* dst; size_t off;
    if (i < 262144)        { src = q;   dst = qb;  off = i; }
    else if (i < 524288)   { src = Ws;  dst = wsb; off = i - 262144; }
    else if (i < 786432)   { src = Wh;  dst = whb; off = i - 524288; }
    else if (i < 1310720)  { src = Wo;  dst = wob; off = i - 786432; }
    else                   { src = enc; dst = eb;  off = i - 1310720; }
    float4 a = *(const float4*)(src + off);
    float4 b = *(const float4*)(src + off + 4);
    ushort4 o0 = make_ushort4((unsigned short)f2b(a.x), (unsigned short)f2b(a.y),
                              (unsigned short)f2b(a.z), (unsigned short)f2b(a.w));
    ushort4 o1 = make_ushort4((unsigned short)f2b(b.x), (unsigned short)f2b(b.y),
                              (unsigned short)f2b(b.z), (unsigned short)f2b(b.w));
    *(ushort4*)(dst + off) = o0;
    *(ushort4*)(dst + off + 4) = o1;
}

// ---- MFMA wave-GEMM core: 32x32 per wave, direct global loads ----
#define MFMA4(APTR0, APTR1, BPTR0, BPTR1, KOFF)                                  \
    {                                                                            \
        bf16x8 a0 = *(const bf16x8*)((APTR0) + (KOFF));                          \
        bf16x8 a1 = *(const bf16x8*)((APTR1) + (KOFF));                          \
        bf16x8 b0 = *(const bf16x8*)((BPTR0) + (KOFF));                          \
        bf16x8 b1 = *(const bf16x8*)((BPTR1) + (KOFF));                          \
        acc00 = __builtin_amdgcn_mfma_f32_16x16x32_bf16(a0, b0, acc00, 0, 0, 0); \
        acc01 = __builtin_amdgcn_mfma_f32_16x16x32_bf16(a0, b1, acc01, 0, 0, 0); \
        acc10 = __builtin_amdgcn_mfma_f32_16x16x32_bf16(a1, b0, acc10, 0, 0, 0); \
        acc11 = __builtin_amdgcn_mfma_f32_16x16x32_bf16(a1, b1, acc11, 0, 0, 0); \
    }

// ---- phase 2: fused projections, qp/kp = bf16(GEMM * QK_SCALE) ----
__global__ __launch_bounds__(64) void mfma_proj(
    const short* __restrict__ qb, const short* __restrict__ eb,
    const short* __restrict__ wsb, const short* __restrict__ whb,
    short* __restrict__ qp, short* __restrict__ kp) {
    const int lane = threadIdx.x;
    const int r = lane & 15, kb = lane >> 4;
    const int n0 = blockIdx.x * 32;
    const int m0 = blockIdx.y * 32;
    const short* A; const short* W; short* C;
    if (m0 < 512) { A = qb + (size_t)m0 * H; W = wsb; C = qp + (size_t)m0 * H; }
    else { A = eb + (size_t)(m0 - 512) * H; W = whb; C = kp + (size_t)(m0 - 512) * H; }
    const short* a0p = A + (size_t)r * H + kb * 8;
    const short* a1p = a0p + 16 * H;
    const short* b0p = W + (size_t)(n0 + r) * H + kb * 8;
    const short* b1p = b0p + 16 * H;
    f32x4 acc00 = {0,0,0,0}, acc01 = {0,0,0,0}, acc10 = {0,0,0,0}, acc11 = {0,0,0,0};
#pragma unroll 4
    for (int k = 0; k < H; k += 32) MFMA4(a0p, a1p, b0p, b1p, k)
    const int cr = kb * 4, cc = r;
#pragma unroll
    for (int g = 0; g < 4; ++g) {
        C[(size_t)(cr + g) * H + n0 + cc]           = f2b(acc00[g] * QK_SCALE);
        C[(size_t)(cr + g) * H + n0 + 16 + cc]      = f2b(acc01[g] * QK_SCALE);
        C[(size_t)(16 + cr + g) * H + n0 + cc]      = f2b(acc10[g] * QK_SCALE);
        C[(size_t)(16 + cr + g) * H + n0 + 16 + cc] = f2b(acc11[g] * QK_SCALE);
    }
}

// ---- phase 3: partial score over one h-half ----
// scoreh[half][b*T+t][s] = -sum_{h in half} 2 v[h] rcp(exp2(qp+kp)+1)
// (qp/kp pre-scaled by 2*log2e; true score differs by softmax-invariant const)
__global__ __launch_bounds__(64) void score_v2(
    const short* __restrict__ qp, const short* __restrict__ kp,
    const float* __restrict__ v, const int* __restrict__ slen,
    float* __restrict__ scoreh) {
    const int half = blockIdx.z & 1;
    const int b = blockIdx.z >> 1;
    const int L = slen[b];
    const int sbase = blockIdx.x * 8;
    if (sbase >= L) return;
    const int tbase = blockIdx.y * 8;
    const int hbase = half * 256;
    // row stride 264 shorts = 528B -> row r starts at bank 4r: 8 rows spread banks
    __shared__ __align__(16) short qs[8][264];
    __shared__ __align__(16) short ks[8][264];
    __shared__ __align__(16) float vsh[256];
    const int lane = threadIdx.x;
    {   // staging: lane covers row r = lane>>3, 32-short chunk at (lane&7)*32
        const int r = lane >> 3, c = (lane & 7) * 32;
        const short* qsrc = qp + (size_t)(b * T + tbase + r) * H + hbase + c;
        const short* ksrc = kp + (size_t)(b * S + sbase + r) * H + hbase + c;
#pragma unroll
        for (int j = 0; j < 4; ++j) {
            *(bf16x8*)&qs[r][c + j * 8] = *(const bf16x8*)(qsrc + j * 8);
            *(bf16x8*)&ks[r][c + j * 8] = *(const bf16x8*)(ksrc + j * 8);
        }
        float4 vv = *(const float4*)&v[hbase + lane * 4];
        *(float4*)&vsh[lane * 4] =
            make_float4(-2.f * vv.x, -2.f * vv.y, -2.f * vv.z, -2.f * vv.w);
    }
    __syncthreads();
    const int t = lane >> 3, s = lane & 7;
    const unsigned int* qrow = (const unsigned int*)&qs[t][0];
    const unsigned int* krow = (const unsigned int*)&ks[s][0];
    float a0 = 0.f, a1 = 0.f, a2 = 0.f, a3 = 0.f;
#pragma unroll 8
    for (int i = 0; i < 128; i += 2) {   // 4 h-elements per iteration
        uint2 qu = *(const uint2*)&qrow[i];
        uint2 ku = *(const uint2*)&krow[i];
        float4 vv = *(const float4*)&vsh[i * 2];
        float e0 = EXP2F(blo(qu.x) + blo(ku.x)) + 1.f;
        float e1 = EXP2F(bhi(qu.x) + bhi(ku.x)) + 1.f;
        float e2 = EXP2F(blo(qu.y) + blo(ku.y)) + 1.f;
        float e3 = EXP2F(bhi(qu.y) + bhi(ku.y)) + 1.f;
        a0 = fmaf(vv.x, __builtin_amdgcn_rcpf(e0), a0);
        a1 = fmaf(vv.y, __builtin_amdgcn_rcpf(e1), a1);
        a2 = fmaf(vv.z, __builtin_amdgcn_rcpf(e2), a2);
        a3 = fmaf(vv.w, __builtin_amdgcn_rcpf(e3), a3);
    }
    scoreh[((size_t)half * (B * T) + b * T + tbase + t) * S + sbase + s] =
        (a0 + a1) + (a2 + a3);
}

// ---- phase 4: fused {enc transpose -> encT bf16} + {softmax(h0+h1) -> attnb bf16} ----
__global__ __launch_bounds__(256) void mid_kernel(
    const float* __restrict__ scoreh, const int* __restrict__ slen,
    short* __restrict__ attnb, const float* __restrict__ enc,
    short* __restrict__ encT) {
    __shared__ short tb[32][33];
    __shared__ float red[8];
    const int bid = blockIdx.x;
    const int tid = threadIdx.x;
    if (bid < 1024) {   // encT[b][h][s] = bf16(enc[b][s][h])
        const int b = bid >> 8, s0 = ((bid >> 4) & 15) * 32, h0 = (bid & 15) * 32;
        const int r = tid >> 3, c = (tid & 7) * 4;
        float4 a = *(const float4*)&enc[((size_t)(b * S + s0 + r)) * H + h0 + c];
        tb[c + 0][r] = f2b(a.x); tb[c + 1][r] = f2b(a.y);
        tb[c + 2][r] = f2b(a.z); tb[c + 3][r] = f2b(a.w);
        __syncthreads();
        ushort4 o = make_ushort4((unsigned short)tb[r][c], (unsigned short)tb[r][c + 1],
                                 (unsigned short)tb[r][c + 2], (unsigned short)tb[r][c + 3]);
        *(ushort4*)&encT[((size_t)(b * H + h0 + r)) * S + s0 + c] = o;
        return;
    }
    const int row = bid - 1024;          // 0..511
    const int L = slen[row >> 7];        // T = 128
    const int lane = tid & 63, wv = tid >> 6;
    const float* p0 = scoreh + (size_t)row * S;
    const float* p1 = p0 + (size_t)(B * T) * S;
    float x0 = p0[tid] + p1[tid];
    float x1 = p0[tid + 256] + p1[tid + 256];
    if (tid >= L) x0 = -INFINITY;
    if (tid + 256 >= L) x1 = -INFINITY;
    float m = fmaxf(x0, x1);
#pragma unroll
    for (int off = 32; off > 0; off >>= 1) m = fmaxf(m, __shfl_xor(m, off));
    if (lane == 0) red[wv] = m;
    __syncthreads();
    m = fmaxf(fmaxf(red[0], red[1]), fmaxf(red[2], red[3]));
    float e0 = __expf(x0 - m);   // native v_exp; masked -inf -> 0
    float e1 = __expf(x1 - m);
    float sm = e0 + e1;
#pragma unroll
    for (int off = 32; off > 0; off >>= 1) sm += __shfl_xor(sm, off);
    if (lane == 0) red[4 + wv] = sm;
    __syncthreads();
    float inv = 1.0f / (red[4] + red[5] + red[6] + red[7]);
    short* o = attnb + (size_t)row * S;
    o[tid] = f2b(e0 * inv);
    o[tid + 256] = f2b(e1 * inv);
}

// ---- phase 5: ctx = attn @ enc (K capped at ceil(L/32)*32; masked attn == 0) ----
__global__ __launch_bounds__(64) void mfma_ctx(
    const short* __restrict__ attnb, const short* __restrict__ encT,
    const int* __restrict__ slen, short* __restrict__ ctxb) {
    const int b = blockIdx.z;
    const int L = slen[b];
    const int Keff = min(S, (L + 31) & ~31);
    const int lane = threadIdx.x;
    const int r = lane & 15, kb = lane >> 4;
    const int m0 = blockIdx.y * 32;
    const int n0 = blockIdx.x * 32;
    const short* A = attnb + (size_t)(b * T + m0) * S;
    const short* Bp = encT + (size_t)b * H * S;
    const short* a0p = A + (size_t)r * S + kb * 8;
    const short* a1p = a0p + 16 * S;
    const short* b0p = Bp + (size_t)(n0 + r) * S + kb * 8;
    const short* b1p = b0p + 16 * S;
    f32x4 acc00 = {0,0,0,0}, acc01 = {0,0,0,0}, acc10 = {0,0,0,0}, acc11 = {0,0,0,0};
#pragma unroll 2
    for (int k = 0; k < Keff; k += 32) MFMA4(a0p, a1p, b0p, b1p, k)
    const int cr = kb * 4, cc = r;
#pragma unroll
    for (int g = 0; g < 4; ++g) {
        size_t row0 = (size_t)(b * T + m0 + cr + g) * H;
        size_t row1 = (size_t)(b * T + m0 + 16 + cr + g) * H;
        ctxb[row0 + n0 + cc]      = f2b(acc00[g]);
        ctxb[row0 + n0 + 16 + cc] = f2b(acc01[g]);
        ctxb[row1 + n0 + cc]      = f2b(acc10[g]);
        ctxb[row1 + n0 + 16 + cc] = f2b(acc11[g]);
    }
}

// ---- phase 6: pre = tanh([ctx|query] @ W_out^T + b) ----
__global__ __launch_bounds__(64) void mfma_out(
    const short* __restrict__ ctxb, const short* __restrict__ qb,
    const short* __restrict__ wob, const float* __restrict__ bias,
    float* __restrict__ pre) {
    const int lane = threadIdx.x;
    const int r = lane & 15, kb = lane >> 4;
    const int m0 = blockIdx.y * 32, n0 = blockIdx.x * 32;
    f32x4 acc00 = {0,0,0,0}, acc01 = {0,0,0,0}, acc10 = {0,0,0,0}, acc11 = {0,0,0,0};
    const short* b0p = wob + (size_t)(n0 + r) * (2 * H) + kb * 8;
    const short* b1p = b0p + 16 * (2 * H);
    {
        const short* a0p = ctxb + (size_t)(m0 + r) * H + kb * 8;
        const short* a1p = a0p + 16 * H;
#pragma unroll 4
        for (int k = 0; k < H; k += 32) MFMA4(a0p, a1p, b0p, b1p, k)
    }
    {
        const short* a0p = qb + (size_t)(m0 + r) * H + kb * 8;
        const short* a1p = a0p + 16 * H;
        const short* c0p = b0p + H;
        const short* c1p = b1p + H;
#pragma unroll 4
        for (int k = 0; k < H; k += 32) MFMA4(a0p, a1p, c0p, c1p, k)
    }
    const int cr = kb * 4, cc = r;
    float bn0 = bias[n0 + cc], bn1 = bias[n0 + 16 + cc];
#pragma unroll
    for (int g = 0; g < 4; ++g) {
        size_t row0 = (size_t)(m0 + cr + g) * H;
        size_t row1 = (size_t)(m0 + 16 + cr + g) * H;
        pre[row0 + n0 + cc]      = fast_tanh(acc00[g] + bn0);
        pre[row0 + n0 + 16 + cc] = fast_tanh(acc01[g] + bn1);
        pre[row1 + n0 + cc]      = fast_tanh(acc10[g] + bn0);
        pre[row1 + n0 + 16 + cc] = fast_tanh(acc11[g] + bn1);
    }
}

// ---- phase 7: per-row LayerNorm ----
__global__ __launch_bounds__(256) void ln_out(
    const float* __restrict__ X, const float* __restrict__ gamma,
    const float* __restrict__ beta, float* __restrict__ out) {
    __shared__ float red[8];
    const int r = blockIdx.x;
    const int tid = threadIdx.x;
    const int lane = tid & 63, wv = tid >> 6;
    const float* x = X + (size_t)r * H;
    float x0 = x[tid], x1 = x[tid + 256];
    float s = x0 + x1;
#pragma unroll
    for (int off = 32; off > 0; off >>= 1) s += __shfl_down(s, off);
    if (lane == 0) red[wv] = s;
    __syncthreads();
    float mu = (red[0] + red[1] + red[2] + red[3]) * (1.0f / H);
    float d0 = x0 - mu, d1 = x1 - mu;
    float vsum = d0 * d0 + d1 * d1;
#pragma unroll
    for (int off = 32; off > 0; off >>= 1) vsum += __shfl_down(vsum, off);
    if (lane == 0) red[4 + wv] = vsum;
    __syncthreads();
    float var = (red[4] + red[5] + red[6] + red[7]) * (1.0f / H);
    float inv = rsqrtf(var + 1e-5f);
    out[(size_t)r * H + tid] = d0 * inv * gamma[tid] + beta[tid];
    out[(size_t)r * H + tid + 256] = d1 * inv * gamma[tid + 256] + beta[tid + 256];
}

extern "C" void kernel_launch(void* const* d_in, const int* in_sizes, int n_in,
                              void* d_out, int out_size, void* d_ws, size_t ws_size,
                              hipStream_t stream) {
    const float* query = (const float*)d_in[0];
    const float* enc   = (const float*)d_in[1];
    const int*   slen  = (const int*)d_in[2];
    const float* W_h   = (const float*)d_in[3];
    const float* W_s   = (const float*)d_in[4];
    const float* v     = (const float*)d_in[5];
    const float* W_out = (const float*)d_in[6];
    const float* b_out = (const float*)d_in[7];
    const float* gamma = (const float*)d_in[8];
    const float* beta  = (const float*)d_in[9];
    float* out = (float*)d_out;

    // ---- aliased workspace map (peak 7.0 MB) ----
    char* base = (char*)d_ws;
    short* qb     = (short*)(base + 0);        // 512KB  bf16 query    [1..6]
    short* wsb    = (short*)(base + 524288);   // 512KB  W_s           [1..2]
    short* ctxb   = (short*)(base + 524288);   //   -> bf16 ctx        [5..6]
    short* whb    = (short*)(base + 1048576);  // 512KB  W_h           [1..2]
    short* attnb  = (short*)(base + 1048576);  //   -> bf16 attn       [4..5]
    short* eb     = (short*)(base + 1572864);  // 2MB    bf16 enc      [1..2]
    float* scoreh = (float*)(base + 1572864);  //   -> f32 score[2]    [3..4]
    float* pre    = (float*)(base + 1572864);  //   -> f32 pre-LN      [6..7]
    short* qp     = (short*)(base + 3670016);  // 512KB  bf16 q_proj   [2..3]
    short* kp     = (short*)(base + 4194304);  // 2MB    bf16 k_proj   [2..3]
    short* encT   = (short*)(base + 4194304);  //   -> bf16 enc^T      [4..5]
    short* wob    = (short*)(base + 6291456);  // 1MB    bf16 W_out    [1..6]

    cvt_all<<<dim3(1152), dim3(256), 0, stream>>>(query, W_s, W_h, W_out, enc,
                                                  qb, wsb, whb, wob, eb);
    mfma_proj<<<dim3(16, 80), dim3(64), 0, stream>>>(qb, eb, wsb, whb, qp, kp);
    // score halves: grid (s-tiles=64, t-tiles=16, b*2 halves=8)
    score_v2<<<dim3(64, 16, 8), dim3(64), 0, stream>>>(qp, kp, v, slen, scoreh);
    // fused encT (blocks 0..1023) + softmax (blocks 1024..1535)
    mid_kernel<<<dim3(1536), dim3(256), 0, stream>>>(scoreh, slen, attnb, enc, encT);
    mfma_ctx<<<dim3(16, 4, 4), dim3(64), 0, stream>>>(attnb, encT, slen, ctxb);
    mfma_out<<<dim3(16, 16), dim3(64), 0, stream>>>(ctxb, qb, wob, b_out, pre);
    ln_out<<<dim3(B * T), dim3(256), 0, stream>>>(pre, gamma, beta, out);
}

// Round 7
// 66.750 us; speedup vs baseline: 3.2735x; 1.2153x over previous
//
#include <hip/hip_runtime.h>
#include <hip/hip_bf16.h>
#include <math.h>

#define B 4
#define T 128
#define S 512
#define H 512
// 2*log2(e): folds tanh's 2x and e->2 base change into the projection epilogue
#define QK_SCALE 2.8853900817779268f

// Hardware exp2 (v_exp_f32). Fallback = native exp path, never OCML-precise.
#if defined(__has_builtin)
#if __has_builtin(__builtin_amdgcn_exp2f)
#define EXP2F(x) __builtin_amdgcn_exp2f(x)
#else
#define EXP2F(x) __expf((x) * 0.6931471805599453f)
#endif
#else
#define EXP2F(x) __expf((x) * 0.6931471805599453f)
#endif

typedef __attribute__((ext_vector_type(8))) short bf16x8;
typedef __attribute__((ext_vector_type(4))) float f32x4;

__device__ __forceinline__ short f2b(float x) {   // f32 -> bf16 RNE
    unsigned int u = __float_as_uint(x);
    u += 0x7fffu + ((u >> 16) & 1u);
    return (short)(u >> 16);
}
__device__ __forceinline__ float fast_tanh(float x) {
    float e = __expf(2.0f * x);
    float r = __builtin_amdgcn_rcpf(e + 1.0f);
    return 1.0f - 2.0f * r;
}

// ---- phase 1: cvt inputs to bf16 (blocks 0..1151) + encT transpose (blocks 1152..2175) ----
__global__ __launch_bounds__(256) void cvt_all(
    const float* __restrict__ q, const float* __restrict__ Ws,
    const float* __restrict__ Wh, const float* __restrict__ Wo,
    const float* __restrict__ enc,
    short* __restrict__ qb, short* __restrict__ wsb, short* __restrict__ whb,
    short* __restrict__ wob, short* __restrict__ eb, short* __restrict__ encT) {
    const int bid = blockIdx.x;
    const int tid = threadIdx.x;
    if (bid >= 1152) {   // encT[b][h][s] = bf16(enc[b][s][h])
        __shared__ short tb[32][33];
        const int bid2 = bid - 1152;
        const int b = bid2 >> 8, s0 = ((bid2 >> 4) & 15) * 32, h0 = (bid2 & 15) * 32;
        const int r = tid >> 3, c = (tid & 7) * 4;
        float4 a = *(const float4*)&enc[((size_t)(b * S + s0 + r)) * H + h0 + c];
        tb[c + 0][r] = f2b(a.x); tb[c + 1][r] = f2b(a.y);
        tb[c + 2][r] = f2b(a.z); tb[c + 3][r] = f2b(a.w);
        __syncthreads();
        ushort4 o = make_ushort4((unsigned short)tb[r][c], (unsigned short)tb[r][c + 1],
                                 (unsigned short)tb[r][c + 2], (unsigned short)tb[r][c + 3]);
        *(ushort4*)&encT[((size_t)(b * H + h0 + r)) * S + s0 + c] = o;
        return;
    }
    size_t i = ((size_t)bid * 256 + tid) * 8;
    const float* src; short* dst; size_t off;
    if (i < 262144)        { src = q;   dst = qb;  off = i; }
    else if (i < 524288)   { src = Ws;  dst = wsb; off = i - 262144; }
    else if (i < 786432)   { src = Wh;  dst = whb; off = i - 524288; }
    else if (i < 1310720)  { src = Wo;  dst = wob; off = i - 786432; }
    else                   { src = enc; dst = eb;  off = i - 1310720; }
    float4 a = *(const float4*)(src + off);
    float4 b = *(const float4*)(src + off + 4);
    ushort4 o0 = make_ushort4((unsigned short)f2b(a.x), (unsigned short)f2b(a.y),
                              (unsigned short)f2b(a.z), (unsigned short)f2b(a.w));
    ushort4 o1 = make_ushort4((unsigned short)f2b(b.x), (unsigned short)f2b(b.y),
                              (unsigned short)f2b(b.z), (unsigned short)f2b(b.w));
    *(ushort4*)(dst + off) = o0;
    *(ushort4*)(dst + off + 4) = o1;
}

// ---- MFMA wave-GEMM core: 32x32 per wave, direct global loads ----
#define MFMA4(APTR0, APTR1, BPTR0, BPTR1, KOFF)                                  \
    {                                                                            \
        bf16x8 a0 = *(const bf16x8*)((APTR0) + (KOFF));                          \
        bf16x8 a1 = *(const bf16x8*)((APTR1) + (KOFF));                          \
        bf16x8 b0 = *(const bf16x8*)((BPTR0) + (KOFF));                          \
        bf16x8 b1 = *(const bf16x8*)((BPTR1) + (KOFF));                          \
        acc00 = __builtin_amdgcn_mfma_f32_16x16x32_bf16(a0, b0, acc00, 0, 0, 0); \
        acc01 = __builtin_amdgcn_mfma_f32_16x16x32_bf16(a0, b1, acc01, 0, 0, 0); \
        acc10 = __builtin_amdgcn_mfma_f32_16x16x32_bf16(a1, b0, acc10, 0, 0, 0); \
        acc11 = __builtin_amdgcn_mfma_f32_16x16x32_bf16(a1, b1, acc11, 0, 0, 0); \
    }

// ---- phase 2: fused projections, Eq/Ek = exp2(GEMM * 2log2e)  (f32) ----
// exp factorization: exp2(q~+k~) = Eq * Ek, so score needs no exp at all.
__global__ __launch_bounds__(64) void mfma_proj(
    const short* __restrict__ qb, const short* __restrict__ eb,
    const short* __restrict__ wsb, const short* __restrict__ whb,
    float* __restrict__ qe, float* __restrict__ ke) {
    const int lane = threadIdx.x;
    const int r = lane & 15, kb = lane >> 4;
    const int n0 = blockIdx.x * 32;
    const int m0 = blockIdx.y * 32;
    const short* A; const short* W; float* C;
    if (m0 < 512) { A = qb + (size_t)m0 * H; W = wsb; C = qe + (size_t)m0 * H; }
    else { A = eb + (size_t)(m0 - 512) * H; W = whb; C = ke + (size_t)(m0 - 512) * H; }
    const short* a0p = A + (size_t)r * H + kb * 8;
    const short* a1p = a0p + 16 * H;
    const short* b0p = W + (size_t)(n0 + r) * H + kb * 8;
    const short* b1p = b0p + 16 * H;
    f32x4 acc00 = {0,0,0,0}, acc01 = {0,0,0,0}, acc10 = {0,0,0,0}, acc11 = {0,0,0,0};
#pragma unroll 4
    for (int k = 0; k < H; k += 32) MFMA4(a0p, a1p, b0p, b1p, k)
    const int cr = kb * 4, cc = r;
#pragma unroll
    for (int g = 0; g < 4; ++g) {
        C[(size_t)(cr + g) * H + n0 + cc]           = EXP2F(acc00[g] * QK_SCALE);
        C[(size_t)(cr + g) * H + n0 + 16 + cc]      = EXP2F(acc01[g] * QK_SCALE);
        C[(size_t)(16 + cr + g) * H + n0 + cc]      = EXP2F(acc10[g] * QK_SCALE);
        C[(size_t)(16 + cr + g) * H + n0 + 16 + cc] = EXP2F(acc11[g] * QK_SCALE);
    }
}

// ---- phase 3: partial score over one h-quarter (128 h) ----
// scoreh[qt][b*T+t][s] = -sum_h 2 v[h] * rcp(Eq[t,h]*Ek[s,h] + 1)
// (true score differs by softmax-invariant const sum(v))
__global__ __launch_bounds__(64) void score_v3(
    const float* __restrict__ qe, const float* __restrict__ ke,
    const float* __restrict__ v, const int* __restrict__ slen,
    float* __restrict__ scoreh) {
    const int qt = blockIdx.z & 3;
    const int b = blockIdx.z >> 2;
    const int L = slen[b];
    const int sbase = blockIdx.x * 8;
    if (sbase >= L) return;
    const int tbase = blockIdx.y * 8;
    const int hbase = qt * 128;
    // stride 132 f32: row r starts at bank 4r; 8 rows x 4-bank b128 reads cover
    // all 32 banks conflict-free; same-row lanes broadcast.
    __shared__ __align__(16) float qs[8][132];
    __shared__ __align__(16) float ks[8][132];
    __shared__ __align__(16) float vsh[128];
    const int lane = threadIdx.x;
    {   // staging: row r = lane>>3, 16-float chunk at (lane&7)*16
        const int r = lane >> 3, c = (lane & 7) * 16;
        const float* qsrc = qe + (size_t)(b * T + tbase + r) * H + hbase + c;
        const float* ksrc = ke + (size_t)(b * S + sbase + r) * H + hbase + c;
#pragma unroll
        for (int j = 0; j < 4; ++j) {
            *(float4*)&qs[r][c + j * 4] = *(const float4*)(qsrc + j * 4);
            *(float4*)&ks[r][c + j * 4] = *(const float4*)(ksrc + j * 4);
        }
        float2 vv = *(const float2*)&v[hbase + lane * 2];
        *(float2*)&vsh[lane * 2] = make_float2(-2.f * vv.x, -2.f * vv.y);
    }
    __syncthreads();
    const int t = lane >> 3, s = lane & 7;
    const float* qrow = &qs[t][0];
    const float* krow = &ks[s][0];
    float a0 = 0.f, a1 = 0.f, a2 = 0.f, a3 = 0.f;
#pragma unroll 4
    for (int i = 0; i < 128; i += 4) {   // per elem: fma, rcp, fma
        float4 q4 = *(const float4*)&qrow[i];
        float4 k4 = *(const float4*)&krow[i];
        float4 v4 = *(const float4*)&vsh[i];
        a0 = fmaf(v4.x, __builtin_amdgcn_rcpf(fmaf(q4.x, k4.x, 1.f)), a0);
        a1 = fmaf(v4.y, __builtin_amdgcn_rcpf(fmaf(q4.y, k4.y, 1.f)), a1);
        a2 = fmaf(v4.z, __builtin_amdgcn_rcpf(fmaf(q4.z, k4.z, 1.f)), a2);
        a3 = fmaf(v4.w, __builtin_amdgcn_rcpf(fmaf(q4.w, k4.w, 1.f)), a3);
    }
    scoreh[((size_t)qt * (B * T) + b * T + tbase + t) * S + sbase + s] =
        (a0 + a1) + (a2 + a3);
}

// ---- phase 4: masked softmax over 4 partial slices, writes bf16 attn ----
__global__ __launch_bounds__(256) void softmax_k(
    const float* __restrict__ scoreh, const int* __restrict__ slen,
    short* __restrict__ attnb) {
    __shared__ float red[8];
    const int row = blockIdx.x;          // 0..511
    const int L = slen[row >> 7];        // T = 128
    const int tid = threadIdx.x;
    const int lane = tid & 63, wv = tid >> 6;
    const size_t sl = (size_t)(B * T) * S;
    const float* p0 = scoreh + (size_t)row * S;
    float x0 = p0[tid] + p0[sl + tid] + p0[2 * sl + tid] + p0[3 * sl + tid];
    float x1 = p0[tid + 256] + p0[sl + tid + 256] + p0[2 * sl + tid + 256] +
               p0[3 * sl + tid + 256];
    if (tid >= L) x0 = -INFINITY;
    if (tid + 256 >= L) x1 = -INFINITY;
    float m = fmaxf(x0, x1);
#pragma unroll
    for (int off = 32; off > 0; off >>= 1) m = fmaxf(m, __shfl_xor(m, off));
    if (lane == 0) red[wv] = m;
    __syncthreads();
    m = fmaxf(fmaxf(red[0], red[1]), fmaxf(red[2], red[3]));
    float e0 = __expf(x0 - m);   // masked -inf -> 0
    float e1 = __expf(x1 - m);
    float sm = e0 + e1;
#pragma unroll
    for (int off = 32; off > 0; off >>= 1) sm += __shfl_xor(sm, off);
    if (lane == 0) red[4 + wv] = sm;
    __syncthreads();
    float inv = 1.0f / (red[4] + red[5] + red[6] + red[7]);
    short* o = attnb + (size_t)row * S;
    o[tid] = f2b(e0 * inv);
    o[tid + 256] = f2b(e1 * inv);
}

// ---- phase 5: ctx = attn @ enc (K capped at ceil(L/32)*32; masked attn == 0) ----
__global__ __launch_bounds__(64) void mfma_ctx(
    const short* __restrict__ attnb, const short* __restrict__ encT,
    const int* __restrict__ slen, short* __restrict__ ctxb) {
    const int b = blockIdx.z;
    const int L = slen[b];
    const int Keff = min(S, (L + 31) & ~31);
    const int lane = threadIdx.x;
    const int r = lane & 15, kb = lane >> 4;
    const int m0 = blockIdx.y * 32;
    const int n0 = blockIdx.x * 32;
    const short* A = attnb + (size_t)(b * T + m0) * S;
    const short* Bp = encT + (size_t)b * H * S;
    const short* a0p = A + (size_t)r * S + kb * 8;
    const short* a1p = a0p + 16 * S;
    const short* b0p = Bp + (size_t)(n0 + r) * S + kb * 8;
    const short* b1p = b0p + 16 * S;
    f32x4 acc00 = {0,0,0,0}, acc01 = {0,0,0,0}, acc10 = {0,0,0,0}, acc11 = {0,0,0,0};
#pragma unroll 2
    for (int k = 0; k < Keff; k += 32) MFMA4(a0p, a1p, b0p, b1p, k)
    const int cr = kb * 4, cc = r;
#pragma unroll
    for (int g = 0; g < 4; ++g) {
        size_t row0 = (size_t)(b * T + m0 + cr + g) * H;
        size_t row1 = (size_t)(b * T + m0 + 16 + cr + g) * H;
        ctxb[row0 + n0 + cc]      = f2b(acc00[g]);
        ctxb[row0 + n0 + 16 + cc] = f2b(acc01[g]);
        ctxb[row1 + n0 + cc]      = f2b(acc10[g]);
        ctxb[row1 + n0 + 16 + cc] = f2b(acc11[g]);
    }
}

// ---- phase 6: pre = tanh([ctx|query] @ W_out^T + b) ----
__global__ __launch_bounds__(64) void mfma_out(
    const short* __restrict__ ctxb, const short* __restrict__ qb,
    const short* __restrict__ wob, const float* __restrict__ bias,
    float* __restrict__ pre) {
    const int lane = threadIdx.x;
    const int r = lane & 15, kb = lane >> 4;
    const int m0 = blockIdx.y * 32, n0 = blockIdx.x * 32;
    f32x4 acc00 = {0,0,0,0}, acc01 = {0,0,0,0}, acc10 = {0,0,0,0}, acc11 = {0,0,0,0};
    const short* b0p = wob + (size_t)(n0 + r) * (2 * H) + kb * 8;
    const short* b1p = b0p + 16 * (2 * H);
    {
        const short* a0p = ctxb + (size_t)(m0 + r) * H + kb * 8;
        const short* a1p = a0p + 16 * H;
#pragma unroll 4
        for (int k = 0; k < H; k += 32) MFMA4(a0p, a1p, b0p, b1p, k)
    }
    {
        const short* a0p = qb + (size_t)(m0 + r) * H + kb * 8;
        const short* a1p = a0p + 16 * H;
        const short* c0p = b0p + H;
        const short* c1p = b1p + H;
#pragma unroll 4
        for (int k = 0; k < H; k += 32) MFMA4(a0p, a1p, c0p, c1p, k)
    }
    const int cr = kb * 4, cc = r;
    float bn0 = bias[n0 + cc], bn1 = bias[n0 + 16 + cc];
#pragma unroll
    for (int g = 0; g < 4; ++g) {
        size_t row0 = (size_t)(m0 + cr + g) * H;
        size_t row1 = (size_t)(m0 + 16 + cr + g) * H;
        pre[row0 + n0 + cc]      = fast_tanh(acc00[g] + bn0);
        pre[row0 + n0 + 16 + cc] = fast_tanh(acc01[g] + bn1);
        pre[row1 + n0 + cc]      = fast_tanh(acc10[g] + bn0);
        pre[row1 + n0 + 16 + cc] = fast_tanh(acc11[g] + bn1);
    }
}

// ---- phase 7: per-row LayerNorm ----
__global__ __launch_bounds__(256) void ln_out(
    const float* __restrict__ X, const float* __restrict__ gamma,
    const float* __restrict__ beta, float* __restrict__ out) {
    __shared__ float red[8];
    const int r = blockIdx.x;
    const int tid = threadIdx.x;
    const int lane = tid & 63, wv = tid >> 6;
    const float* x = X + (size_t)r * H;
    float x0 = x[tid], x1 = x[tid + 256];
    float s = x0 + x1;
#pragma unroll
    for (int off = 32; off > 0; off >>= 1) s += __shfl_down(s, off);
    if (lane == 0) red[wv] = s;
    __syncthreads();
    float mu = (red[0] + red[1] + red[2] + red[3]) * (1.0f / H);
    float d0 = x0 - mu, d1 = x1 - mu;
    float vsum = d0 * d0 + d1 * d1;
#pragma unroll
    for (int off = 32; off > 0; off >>= 1) vsum += __shfl_down(vsum, off);
    if (lane == 0) red[4 + wv] = vsum;
    __syncthreads();
    float var = (red[4] + red[5] + red[6] + red[7]) * (1.0f / H);
    float inv = rsqrtf(var + 1e-5f);
    out[(size_t)r * H + tid] = d0 * inv * gamma[tid] + beta[tid];
    out[(size_t)r * H + tid + 256] = d1 * inv * gamma[tid + 256] + beta[tid + 256];
}

extern "C" void kernel_launch(void* const* d_in, const int* in_sizes, int n_in,
                              void* d_out, int out_size, void* d_ws, size_t ws_size,
                              hipStream_t stream) {
    const float* query = (const float*)d_in[0];
    const float* enc   = (const float*)d_in[1];
    const int*   slen  = (const int*)d_in[2];
    const float* W_h   = (const float*)d_in[3];
    const float* W_s   = (const float*)d_in[4];
    const float* v     = (const float*)d_in[5];
    const float* W_out = (const float*)d_in[6];
    const float* b_out = (const float*)d_in[7];
    const float* gamma = (const float*)d_in[8];
    const float* beta  = (const float*)d_in[9];
    float* out = (float*)d_out;

    // ---- workspace map, non-aliased, 17.5 MB (d_ws is 256 MB per R6 profile) ----
    char* base = (char*)d_ws;
    short* qb     = (short*)(base + 0);          // 512K  bf16 query
    short* wsb    = (short*)(base + 524288);     // 512K  bf16 W_s
    short* whb    = (short*)(base + 1048576);    // 512K  bf16 W_h
    short* wob    = (short*)(base + 1572864);    // 1M    bf16 W_out
    short* eb     = (short*)(base + 2621440);    // 2M    bf16 enc
    float* qe     = (float*)(base + 4718592);    // 1M    f32 exp2(q_proj~)
    float* ke     = (float*)(base + 5767168);    // 4M    f32 exp2(k_proj~)
    float* scoreh = (float*)(base + 9961472);    // 4M    f32 score quarters
    short* attnb  = (short*)(base + 14155776);   // 512K  bf16 attn
    short* encT   = (short*)(base + 14680064);   // 2M    bf16 enc^T
    short* ctxb   = (short*)(base + 16777216);   // 512K  bf16 ctx
    float* pre    = (float*)(base + 17301504);   // 1M    f32 pre-LN

    // cvt (1152 blocks) + encT transpose (1024 blocks)
    cvt_all<<<dim3(2176), dim3(256), 0, stream>>>(query, W_s, W_h, W_out, enc,
                                                  qb, wsb, whb, wob, eb, encT);
    mfma_proj<<<dim3(16, 80), dim3(64), 0, stream>>>(qb, eb, wsb, whb, qe, ke);
    // score quarters: grid (s-tiles=64, t-tiles=16, b*4 quarters=16)
    score_v3<<<dim3(64, 16, 16), dim3(64), 0, stream>>>(qe, ke, v, slen, scoreh);
    softmax_k<<<dim3(B * T), dim3(256), 0, stream>>>(scoreh, slen, attnb);
    mfma_ctx<<<dim3(16, 4, 4), dim3(64), 0, stream>>>(attnb, encT, slen, ctxb);
    mfma_out<<<dim3(16, 16), dim3(64), 0, stream>>>(ctxb, qb, wob, b_out, pre);
    ln_out<<<dim3(B * T), dim3(256), 0, stream>>>(pre, gamma, beta, out);
}